// Round 5
// baseline (324.904 us; speedup 1.0000x reference)
//
#include <hip/hip_runtime.h>
#include <hip/hip_bf16.h>

#define N_SEND 49152
#define N_REC  65536
#define N_EDGES 262144
#define D_MODEL 256
#define EDGE_IN 4
#define EDGE_OUT 64
#define LIN_IN 320
#define LIN_OUT 256
#define BATCH 2

#define EPB 32   // edges per block in edge MLP kernel

typedef __attribute__((ext_vector_type(4))) float f32x4;
typedef __attribute__((ext_vector_type(8))) short bf16x8;

static __device__ __forceinline__ unsigned short f2bf(float f) {
    union { float f; unsigned u; } v; v.f = f;
    unsigned r = v.u + 0x7FFF + ((v.u >> 16) & 1);   // round-to-nearest-even
    return (unsigned short)(r >> 16);
}
static __device__ __forceinline__ float bf2f(unsigned short h) {
    union { unsigned u; float f; } v; v.u = ((unsigned)h) << 16; return v.f;
}

// ---------------------------------------------------------------------------
// x (f32, [2][49152][256]) -> xb (bf16), 8 elems/thread.
__global__ __launch_bounds__(256) void conv_x_kernel(
    const float* __restrict__ x, unsigned short* __restrict__ xb)
{
    const size_t i = ((size_t)blockIdx.x * 256 + threadIdx.x) * 8;
    const float4 v0 = *(const float4*)&x[i];
    const float4 v1 = *(const float4*)&x[i + 4];
    bf16x8 o;
    o[0] = (short)f2bf(v0.x); o[1] = (short)f2bf(v0.y);
    o[2] = (short)f2bf(v0.z); o[3] = (short)f2bf(v0.w);
    o[4] = (short)f2bf(v1.x); o[5] = (short)f2bf(v1.y);
    o[6] = (short)f2bf(v1.z); o[7] = (short)f2bf(v1.w);
    *(bf16x8*)&xb[i] = o;
}

// ---------------------------------------------------------------------------
// Edge MLP (4->64 relu ->64) -> efs[e][64] bf16 (vectorized stores via LDS
// transpose), plus receiver histogram.
__global__ __launch_bounds__(256) void edge_mlp_kernel(
    const int* __restrict__ receivers,
    const float* __restrict__ edge_attr,
    const float* __restrict__ ee_w1, const float* __restrict__ ee_b1,
    const float* __restrict__ ee_w2, const float* __restrict__ ee_b2,
    unsigned short* __restrict__ efs, int* __restrict__ counts)
{
    __shared__ float h_lds[EPB][EDGE_OUT];
    __shared__ float e_lds[EPB][EDGE_OUT];

    const int tid = threadIdx.x;
    const int e0 = blockIdx.x * EPB;

    if (tid < EPB) atomicAdd(&counts[receivers[e0 + tid]], 1);

    // h = relu(edge_attr @ ee_w1 + ee_b1)
    for (int i = tid; i < EPB * EDGE_OUT; i += 256) {
        const int e = i >> 6, j = i & 63;
        const float* ea = edge_attr + (size_t)(e0 + e) * EDGE_IN;
        float acc = ee_b1[j];
        acc += ea[0] * ee_w1[0 * EDGE_OUT + j];
        acc += ea[1] * ee_w1[1 * EDGE_OUT + j];
        acc += ea[2] * ee_w1[2 * EDGE_OUT + j];
        acc += ea[3] * ee_w1[3 * EDGE_OUT + j];
        h_lds[e][j] = fmaxf(acc, 0.0f);
    }
    __syncthreads();

    // ef = h @ ee_w2 + ee_b2 -> e_lds (f32)
    {
        const int j = tid & 63, g = tid >> 6;
        float acc[8];
#pragma unroll
        for (int e = 0; e < 8; ++e) acc[e] = ee_b2[j];
        for (int k = 0; k < EDGE_OUT; ++k) {
            const float w = ee_w2[k * EDGE_OUT + j];
#pragma unroll
            for (int e = 0; e < 8; ++e) acc[e] += h_lds[g * 8 + e][k] * w;
        }
#pragma unroll
        for (int e = 0; e < 8; ++e) e_lds[g * 8 + e][j] = acc[e];
    }
    __syncthreads();

    // vectorized bf16 store: thread t -> edge e=t>>3, segment seg=t&7
    {
        const int e = tid >> 3, seg = tid & 7;
        const float* src = &e_lds[e][seg * 8];
        bf16x8 o;
#pragma unroll
        for (int j = 0; j < 8; ++j) o[j] = (short)f2bf(src[j]);
        *(bf16x8*)&efs[(size_t)(e0 + e) * EDGE_OUT + seg * 8] = o;
    }
}

// ---------------------------------------------------------------------------
// Exclusive scan of counts[65536] -> row_ptr[65537], copy to cursor.
__global__ __launch_bounds__(1024) void scan_kernel(
    const int* __restrict__ counts, int* __restrict__ row_ptr,
    int* __restrict__ cursor)
{
    __shared__ int sums[1024];
    const int t = threadIdx.x;
    const int4* c4 = (const int4*)(counts + t * 64);

    int s = 0;
#pragma unroll
    for (int i = 0; i < 16; ++i) { const int4 c = c4[i]; s += c.x + c.y + c.z + c.w; }
    sums[t] = s;
    __syncthreads();

    for (int off = 1; off < 1024; off <<= 1) {
        const int v = (t >= off) ? sums[t - off] : 0;
        __syncthreads();
        sums[t] += v;
        __syncthreads();
    }

    int run = sums[t] - s;   // exclusive prefix of this thread's chunk
#pragma unroll
    for (int i = 0; i < 16; ++i) {
        const int4 c = c4[i];
        int4 w;
        w.x = run; w.y = run + c.x; w.z = w.y + c.y; w.w = w.z + c.z;
        run = w.w + c.w;
        ((int4*)(row_ptr + t * 64))[i] = w;
        ((int4*)(cursor + t * 64))[i] = w;
    }
    if (t == 1023) row_ptr[N_REC] = run;
}

// ---------------------------------------------------------------------------
// Bucket edges by receiver: edge_order[pos]=e, ssort[pos]=senders[e].
__global__ __launch_bounds__(256) void fill_kernel(
    const int* __restrict__ senders, const int* __restrict__ receivers,
    int* __restrict__ cursor, int* __restrict__ edge_order,
    int* __restrict__ ssort)
{
    const int e = blockIdx.x * 256 + threadIdx.x;
    const int r = receivers[e];
    const int pos = atomicAdd(&cursor[r], 1);
    edge_order[pos] = e;
    ssort[pos] = senders[e];
}

// ---------------------------------------------------------------------------
// Wave-per-receiver gather: lanes 0..31 = batch 0 row, lanes 32..63 = batch 1
// row, 16B/lane loads; indices broadcast via __shfl so row loads pipeline.
// Lanes 0..7 also accumulate the 64-col edge-feature sum (shared by batches).
template<bool XB>
__global__ __launch_bounds__(256) void gather_kernel(
    const float* __restrict__ x,
    const unsigned short* __restrict__ xb,
    const unsigned short* __restrict__ efs,
    const int* __restrict__ row_ptr,
    const int* __restrict__ edge_order,
    const int* __restrict__ ssort,
    unsigned short* __restrict__ vmb)
{
    const int lane = threadIdx.x & 63;
    const int wave = threadIdx.x >> 6;
    const int r = blockIdx.x * 4 + wave;
    const int beg = row_ptr[r], end = row_ptr[r + 1];
    const int half = lane >> 5, l2 = lane & 31;

    float ax[8] = {0, 0, 0, 0, 0, 0, 0, 0};
    float ae[8] = {0, 0, 0, 0, 0, 0, 0, 0};

    for (int chunk = beg; chunk < end; chunk += 64) {
        const int n = min(64, end - chunk);
        int myidx = 0, myeidx = 0;
        if (chunk + lane < end) {
            myidx = ssort[chunk + lane];
            myeidx = edge_order[chunk + lane];
        }
        for (int i = 0; i < n; ++i) {
            const int s = __shfl(myidx, i);
            const int e = __shfl(myeidx, i);
            const size_t rowbase = (size_t)(half ? N_SEND + s : s) * D_MODEL;
            if (XB) {
                const bf16x8 v = *(const bf16x8*)&xb[rowbase + l2 * 8];
#pragma unroll
                for (int j = 0; j < 8; ++j) ax[j] += bf2f((unsigned short)v[j]);
            } else {
                const float4 v0 = *(const float4*)&x[rowbase + l2 * 8];
                const float4 v1 = *(const float4*)&x[rowbase + l2 * 8 + 4];
                ax[0] += v0.x; ax[1] += v0.y; ax[2] += v0.z; ax[3] += v0.w;
                ax[4] += v1.x; ax[5] += v1.y; ax[6] += v1.z; ax[7] += v1.w;
            }
            if (lane < 8) {
                const bf16x8 w = *(const bf16x8*)&efs[(size_t)e * EDGE_OUT + lane * 8];
#pragma unroll
                for (int j = 0; j < 8; ++j) ae[j] += bf2f((unsigned short)w[j]);
            }
        }
    }

    bf16x8 o;
#pragma unroll
    for (int j = 0; j < 8; ++j) o[j] = (short)f2bf(ax[j]);
    *(bf16x8*)&vmb[((size_t)(half * N_REC + r)) * LIN_IN + l2 * 8] = o;
    if (lane < 8) {
        bf16x8 oe;
#pragma unroll
        for (int j = 0; j < 8; ++j) oe[j] = (short)f2bf(ae[j]);
        *(bf16x8*)&vmb[((size_t)r) * LIN_IN + D_MODEL + lane * 8] = oe;
        *(bf16x8*)&vmb[((size_t)(N_REC + r)) * LIN_IN + D_MODEL + lane * 8] = oe;
    }
}

// ---------------------------------------------------------------------------
// Weight prep: w1t[n][k] = bf16(ff_w1[k][n]) (256x320),
//              w2t[n][k] = bf16(ff_w2[k][n]) (256x256)
__global__ __launch_bounds__(256) void prep_weights(
    const float* __restrict__ w1, const float* __restrict__ w2,
    unsigned short* __restrict__ w1t, unsigned short* __restrict__ w2t)
{
    const int tid = blockIdx.x * 256 + threadIdx.x;
    if (tid < 256 * LIN_IN) {
        const int n = tid / LIN_IN, k = tid - n * LIN_IN;
        w1t[tid] = f2bf(w1[k * LIN_OUT + n]);
    } else {
        const int t2 = tid - 256 * LIN_IN;
        if (t2 < 256 * 256) {
            const int n = t2 >> 8, k = t2 & 255;
            w2t[t2] = f2bf(w2[k * LIN_OUT + n]);
        }
    }
}

// ---------------------------------------------------------------------------
// MFMA node MLP with explicit 2-deep register software pipeline:
// per iteration {load(B,k+1); mfma(A); load(A,k+2); mfma(B)} so each MFMA
// cluster consumes fragments whose loads were issued a full chunk earlier
// (counted-vmcnt keeps the younger 8 loads in flight).
// A-frag: lane holds A[m=lane&15][k = kk + (lane>>4)*8 + j]; B same map.
// C/D: row = 4*(lane>>4)+reg, col = lane&15.
#define BM 64
#define HPAD 264

__global__ __launch_bounds__(256, 3) void node_mlp_mfma(
    const unsigned short* __restrict__ vmb,   // [2*N_REC][320] bf16
    const unsigned short* __restrict__ w1t,   // [256][320] bf16
    const float* __restrict__ b1,
    const unsigned short* __restrict__ w2t,   // [256][256] bf16
    const float* __restrict__ b2,
    float* __restrict__ out)
{
    __shared__ __align__(16) unsigned short h_lds[BM * HPAD];   // 33 KB

    const int tid  = threadIdx.x;
    const int wave = tid >> 6, lane = tid & 63;
    const int n16  = lane & 15, hi = lane >> 4;
    const int wcol = wave * 64;
    const size_t row0 = (size_t)blockIdx.x * BM;

    const unsigned short* wp1 = w1t + (size_t)(wcol + n16) * LIN_IN + hi * 8;
    const unsigned short* ap1 = vmb + (row0 + n16) * LIN_IN + hi * 8;

    auto l1_load = [&](bf16x8 (&af)[4], bf16x8 (&bf)[4], int kk) {
#pragma unroll
        for (int c = 0; c < 4; ++c)
            bf[c] = *(const bf16x8*)&wp1[(size_t)(16 * c) * LIN_IN + kk];
#pragma unroll
        for (int t = 0; t < 4; ++t)
            af[t] = *(const bf16x8*)&ap1[(size_t)(16 * t) * LIN_IN + kk];
    };
    auto l2_load = [&](bf16x8 (&af)[4], bf16x8 (&bf)[4], int kk) {
#pragma unroll
        for (int c = 0; c < 4; ++c)
            bf[c] = *(const bf16x8*)&w2t[(size_t)(wcol + 16 * c + n16) * LIN_OUT + kk + hi * 8];
#pragma unroll
        for (int t = 0; t < 4; ++t)
            af[t] = *(const bf16x8*)&h_lds[(16 * t + n16) * HPAD + kk + hi * 8];
    };

    // ---- Layer 1: h = relu(vm @ w1 + b1), K=320, 10 chunks of 32 ----
    f32x4 acc[4][4];
#pragma unroll
    for (int c = 0; c < 4; ++c) {
        const float bv = b1[wcol + 16 * c + n16];
#pragma unroll
        for (int t = 0; t < 4; ++t) {
            acc[t][c][0] = bv; acc[t][c][1] = bv; acc[t][c][2] = bv; acc[t][c][3] = bv;
        }
    }

    auto l1_mfma = [&](bf16x8 (&af)[4], bf16x8 (&bf)[4]) {
#pragma unroll
        for (int c = 0; c < 4; ++c)
#pragma unroll
            for (int t = 0; t < 4; ++t)
                acc[t][c] = __builtin_amdgcn_mfma_f32_16x16x32_bf16(af[t], bf[c], acc[t][c], 0, 0, 0);
    };

    {
        bf16x8 afA[4], bfA[4], afB[4], bfB[4];
        l1_load(afA, bfA, 0);
        for (int kk = 0; kk < LIN_IN - 64; kk += 64) {   // kk = 0,64,128,192
            l1_load(afB, bfB, kk + 32);
            l1_mfma(afA, bfA);
            l1_load(afA, bfA, kk + 64);
            l1_mfma(afB, bfB);
        }
        l1_load(afB, bfB, LIN_IN - 32);
        l1_mfma(afA, bfA);
        l1_mfma(afB, bfB);
    }

    // relu -> h_lds (bf16). C/D: row = 16t + 4hi + reg, col = wcol + 16c + n16.
#pragma unroll
    for (int t = 0; t < 4; ++t)
#pragma unroll
        for (int c = 0; c < 4; ++c)
#pragma unroll
            for (int r = 0; r < 4; ++r)
                h_lds[(16 * t + 4 * hi + r) * HPAD + wcol + 16 * c + n16] =
                    f2bf(fmaxf(acc[t][c][r], 0.0f));
    __syncthreads();

    // ---- Layer 2: out = h @ w2 + b2, K=256, 8 chunks of 32 ----
    f32x4 acc2[4][4];
#pragma unroll
    for (int c = 0; c < 4; ++c) {
        const float bv = b2[wcol + 16 * c + n16];
#pragma unroll
        for (int t = 0; t < 4; ++t) {
            acc2[t][c][0] = bv; acc2[t][c][1] = bv; acc2[t][c][2] = bv; acc2[t][c][3] = bv;
        }
    }

    auto l2_mfma = [&](bf16x8 (&af)[4], bf16x8 (&bf)[4]) {
#pragma unroll
        for (int c = 0; c < 4; ++c)
#pragma unroll
            for (int t = 0; t < 4; ++t)
                acc2[t][c] = __builtin_amdgcn_mfma_f32_16x16x32_bf16(af[t], bf[c], acc2[t][c], 0, 0, 0);
    };

    {
        bf16x8 afA[4], bfA[4], afB[4], bfB[4];
        l2_load(afA, bfA, 0);
        for (int kk = 0; kk < LIN_OUT - 64; kk += 64) {  // kk = 0,64,128
            l2_load(afB, bfB, kk + 32);
            l2_mfma(afA, bfA);
            l2_load(afA, bfA, kk + 64);
            l2_mfma(afB, bfB);
        }
        l2_load(afB, bfB, LIN_OUT - 32);
        l2_mfma(afA, bfA);
        l2_mfma(afB, bfB);
    }

#pragma unroll
    for (int t = 0; t < 4; ++t)
#pragma unroll
        for (int c = 0; c < 4; ++c)
#pragma unroll
            for (int r = 0; r < 4; ++r)
                out[(row0 + 16 * t + 4 * hi + r) * LIN_OUT + wcol + 16 * c + n16] = acc2[t][c][r];
}

// ---------------------------------------------------------------------------
extern "C" void kernel_launch(void* const* d_in, const int* in_sizes, int n_in,
                              void* d_out, int out_size, void* d_ws, size_t ws_size,
                              hipStream_t stream) {
    const float* x         = (const float*)d_in[0];
    const int*   edge_idx  = (const int*)d_in[1];
    const float* edge_attr = (const float*)d_in[2];
    const float* ee_w1     = (const float*)d_in[3];
    const float* ee_b1     = (const float*)d_in[4];
    const float* ee_w2     = (const float*)d_in[5];
    const float* ee_b2     = (const float*)d_in[6];
    const float* ff_w1     = (const float*)d_in[7];
    const float* ff_b1     = (const float*)d_in[8];
    const float* ff_w2     = (const float*)d_in[9];
    const float* ff_b2     = (const float*)d_in[10];
    float* out = (float*)d_out;

    const int* senders   = edge_idx;
    const int* receivers = edge_idx + N_EDGES;

    // Workspace layout (512B-aligned sub-buffers).
    char* ws = (char*)d_ws;
    size_t off = 0;
    auto alloc = [&](size_t bytes) { char* p = ws + off; off += (bytes + 511) & ~511ull; return p; };

    unsigned short* vmb = (unsigned short*)alloc((size_t)BATCH * N_REC * LIN_IN * 2);   // 83.9 MB
    unsigned short* efs = (unsigned short*)alloc((size_t)N_EDGES * EDGE_OUT * 2);       // 33.6 MB
    unsigned short* w1t = (unsigned short*)alloc((size_t)256 * LIN_IN * 2);
    unsigned short* w2t = (unsigned short*)alloc((size_t)256 * LIN_OUT * 2);
    int* row_ptr        = (int*)alloc((size_t)(N_REC + 1) * 4);
    int* counts         = (int*)alloc((size_t)N_REC * 4);
    int* cursor         = (int*)alloc((size_t)N_REC * 4);
    int* edge_order     = (int*)alloc((size_t)N_EDGES * 4);
    int* ssort          = (int*)alloc((size_t)N_EDGES * 4);
    const size_t base_need = off;
    unsigned short* xb  = (unsigned short*)(ws + off);
    const size_t xb_bytes = (size_t)BATCH * N_SEND * D_MODEL * 2;                        // 50.3 MB
    const bool use_xb = (ws_size >= base_need + xb_bytes);

    hipMemsetAsync(counts, 0, (size_t)N_REC * 4, stream);

    prep_weights<<<(256 * LIN_IN + 256 * LIN_OUT + 255) / 256, 256, 0, stream>>>(
        ff_w1, ff_w2, w1t, w2t);

    if (use_xb) {
        conv_x_kernel<<<(int)((size_t)BATCH * N_SEND * D_MODEL / 8 / 256), 256, 0, stream>>>(x, xb);
    }

    edge_mlp_kernel<<<N_EDGES / EPB, 256, 0, stream>>>(
        receivers, edge_attr, ee_w1, ee_b1, ee_w2, ee_b2, efs, counts);

    scan_kernel<<<1, 1024, 0, stream>>>(counts, row_ptr, cursor);

    fill_kernel<<<N_EDGES / 256, 256, 0, stream>>>(
        senders, receivers, cursor, edge_order, ssort);

    if (use_xb) {
        gather_kernel<true><<<N_REC / 4, 256, 0, stream>>>(
            x, xb, efs, row_ptr, edge_order, ssort, vmb);
    } else {
        gather_kernel<false><<<N_REC / 4, 256, 0, stream>>>(
            x, xb, efs, row_ptr, edge_order, ssort, vmb);
    }

    node_mlp_mfma<<<(BATCH * N_REC) / BM, 256, 0, stream>>>(
        vmb, w1t, ff_b1, w2t, ff_b2, out);
}

// Round 6
// 285.650 us; speedup vs baseline: 1.1374x; 1.1374x over previous
//
#include <hip/hip_runtime.h>
#include <hip/hip_bf16.h>

#define N_SEND 49152
#define N_REC  65536
#define N_EDGES 262144
#define D_MODEL 256
#define EDGE_IN 4
#define EDGE_OUT 64
#define LIN_IN 320
#define LIN_OUT 256
#define BATCH 2

#define EPB 32   // edges per block in edge MLP kernel
#define GBM 128  // rows per block in node GEMM kernels

typedef __attribute__((ext_vector_type(4))) float f32x4;
typedef __attribute__((ext_vector_type(8))) short bf16x8;

static __device__ __forceinline__ unsigned short f2bf(float f) {
    union { float f; unsigned u; } v; v.f = f;
    unsigned r = v.u + 0x7FFF + ((v.u >> 16) & 1);   // round-to-nearest-even
    return (unsigned short)(r >> 16);
}
static __device__ __forceinline__ float bf2f(unsigned short h) {
    union { unsigned u; float f; } v; v.u = ((unsigned)h) << 16; return v.f;
}

// async global->LDS, 16B per lane; LDS dest = wave-uniform base + lane*16
static __device__ __forceinline__ void async_copy16(void* lds_ptr, const void* g_ptr) {
    __builtin_amdgcn_global_load_lds(
        (const __attribute__((address_space(1))) void*)g_ptr,
        (__attribute__((address_space(3))) void*)lds_ptr, 16, 0, 0);
}

// ---------------------------------------------------------------------------
// x (f32, [2][49152][256]) -> xb (bf16), 8 elems/thread.
__global__ __launch_bounds__(256) void conv_x_kernel(
    const float* __restrict__ x, unsigned short* __restrict__ xb)
{
    const size_t i = ((size_t)blockIdx.x * 256 + threadIdx.x) * 8;
    const float4 v0 = *(const float4*)&x[i];
    const float4 v1 = *(const float4*)&x[i + 4];
    bf16x8 o;
    o[0] = (short)f2bf(v0.x); o[1] = (short)f2bf(v0.y);
    o[2] = (short)f2bf(v0.z); o[3] = (short)f2bf(v0.w);
    o[4] = (short)f2bf(v1.x); o[5] = (short)f2bf(v1.y);
    o[6] = (short)f2bf(v1.z); o[7] = (short)f2bf(v1.w);
    *(bf16x8*)&xb[i] = o;
}

// ---------------------------------------------------------------------------
// Edge MLP (4->64 relu ->64) -> efs[e][64] bf16, plus receiver histogram.
__global__ __launch_bounds__(256) void edge_mlp_kernel(
    const int* __restrict__ receivers,
    const float* __restrict__ edge_attr,
    const float* __restrict__ ee_w1, const float* __restrict__ ee_b1,
    const float* __restrict__ ee_w2, const float* __restrict__ ee_b2,
    unsigned short* __restrict__ efs, int* __restrict__ counts)
{
    __shared__ float h_lds[EPB][EDGE_OUT];
    __shared__ float e_lds[EPB][EDGE_OUT];

    const int tid = threadIdx.x;
    const int e0 = blockIdx.x * EPB;

    if (tid < EPB) atomicAdd(&counts[receivers[e0 + tid]], 1);

    for (int i = tid; i < EPB * EDGE_OUT; i += 256) {
        const int e = i >> 6, j = i & 63;
        const float* ea = edge_attr + (size_t)(e0 + e) * EDGE_IN;
        float acc = ee_b1[j];
        acc += ea[0] * ee_w1[0 * EDGE_OUT + j];
        acc += ea[1] * ee_w1[1 * EDGE_OUT + j];
        acc += ea[2] * ee_w1[2 * EDGE_OUT + j];
        acc += ea[3] * ee_w1[3 * EDGE_OUT + j];
        h_lds[e][j] = fmaxf(acc, 0.0f);
    }
    __syncthreads();

    {
        const int j = tid & 63, g = tid >> 6;
        float acc[8];
#pragma unroll
        for (int e = 0; e < 8; ++e) acc[e] = ee_b2[j];
        for (int k = 0; k < EDGE_OUT; ++k) {
            const float w = ee_w2[k * EDGE_OUT + j];
#pragma unroll
            for (int e = 0; e < 8; ++e) acc[e] += h_lds[g * 8 + e][k] * w;
        }
#pragma unroll
        for (int e = 0; e < 8; ++e) e_lds[g * 8 + e][j] = acc[e];
    }
    __syncthreads();

    {
        const int e = tid >> 3, seg = tid & 7;
        const float* src = &e_lds[e][seg * 8];
        bf16x8 o;
#pragma unroll
        for (int j = 0; j < 8; ++j) o[j] = (short)f2bf(src[j]);
        *(bf16x8*)&efs[(size_t)(e0 + e) * EDGE_OUT + seg * 8] = o;
    }
}

// ---------------------------------------------------------------------------
// Exclusive scan of counts[65536] -> row_ptr[65537], copy to cursor.
__global__ __launch_bounds__(1024) void scan_kernel(
    const int* __restrict__ counts, int* __restrict__ row_ptr,
    int* __restrict__ cursor)
{
    __shared__ int sums[1024];
    const int t = threadIdx.x;
    const int4* c4 = (const int4*)(counts + t * 64);

    int s = 0;
#pragma unroll
    for (int i = 0; i < 16; ++i) { const int4 c = c4[i]; s += c.x + c.y + c.z + c.w; }
    sums[t] = s;
    __syncthreads();

    for (int off = 1; off < 1024; off <<= 1) {
        const int v = (t >= off) ? sums[t - off] : 0;
        __syncthreads();
        sums[t] += v;
        __syncthreads();
    }

    int run = sums[t] - s;
#pragma unroll
    for (int i = 0; i < 16; ++i) {
        const int4 c = c4[i];
        int4 w;
        w.x = run; w.y = run + c.x; w.z = w.y + c.y; w.w = w.z + c.z;
        run = w.w + c.w;
        ((int4*)(row_ptr + t * 64))[i] = w;
        ((int4*)(cursor + t * 64))[i] = w;
    }
    if (t == 1023) row_ptr[N_REC] = run;
}

// ---------------------------------------------------------------------------
// Bucket edges by receiver: edge_order[pos]=e, ssort[pos]=senders[e].
__global__ __launch_bounds__(256) void fill_kernel(
    const int* __restrict__ senders, const int* __restrict__ receivers,
    int* __restrict__ cursor, int* __restrict__ edge_order,
    int* __restrict__ ssort)
{
    const int e = blockIdx.x * 256 + threadIdx.x;
    const int r = receivers[e];
    const int pos = atomicAdd(&cursor[r], 1);
    edge_order[pos] = e;
    ssort[pos] = senders[e];
}

// ---------------------------------------------------------------------------
// Wave-per-receiver gather (unchanged this round).
template<bool XB>
__global__ __launch_bounds__(256) void gather_kernel(
    const float* __restrict__ x,
    const unsigned short* __restrict__ xb,
    const unsigned short* __restrict__ efs,
    const int* __restrict__ row_ptr,
    const int* __restrict__ edge_order,
    const int* __restrict__ ssort,
    unsigned short* __restrict__ vmb)
{
    const int lane = threadIdx.x & 63;
    const int wave = threadIdx.x >> 6;
    const int r = blockIdx.x * 4 + wave;
    const int beg = row_ptr[r], end = row_ptr[r + 1];
    const int half = lane >> 5, l2 = lane & 31;

    float ax[8] = {0, 0, 0, 0, 0, 0, 0, 0};
    float ae[8] = {0, 0, 0, 0, 0, 0, 0, 0};

    for (int chunk = beg; chunk < end; chunk += 64) {
        const int n = min(64, end - chunk);
        int myidx = 0, myeidx = 0;
        if (chunk + lane < end) {
            myidx = ssort[chunk + lane];
            myeidx = edge_order[chunk + lane];
        }
        for (int i = 0; i < n; ++i) {
            const int s = __shfl(myidx, i);
            const int e = __shfl(myeidx, i);
            const size_t rowbase = (size_t)(half ? N_SEND + s : s) * D_MODEL;
            if (XB) {
                const bf16x8 v = *(const bf16x8*)&xb[rowbase + l2 * 8];
#pragma unroll
                for (int j = 0; j < 8; ++j) ax[j] += bf2f((unsigned short)v[j]);
            } else {
                const float4 v0 = *(const float4*)&x[rowbase + l2 * 8];
                const float4 v1 = *(const float4*)&x[rowbase + l2 * 8 + 4];
                ax[0] += v0.x; ax[1] += v0.y; ax[2] += v0.z; ax[3] += v0.w;
                ax[4] += v1.x; ax[5] += v1.y; ax[6] += v1.z; ax[7] += v1.w;
            }
            if (lane < 8) {
                const bf16x8 w = *(const bf16x8*)&efs[(size_t)e * EDGE_OUT + lane * 8];
#pragma unroll
                for (int j = 0; j < 8; ++j) ae[j] += bf2f((unsigned short)w[j]);
            }
        }
    }

    bf16x8 o;
#pragma unroll
    for (int j = 0; j < 8; ++j) o[j] = (short)f2bf(ax[j]);
    *(bf16x8*)&vmb[((size_t)(half * N_REC + r)) * LIN_IN + l2 * 8] = o;
    if (lane < 8) {
        bf16x8 oe;
#pragma unroll
        for (int j = 0; j < 8; ++j) oe[j] = (short)f2bf(ae[j]);
        *(bf16x8*)&vmb[((size_t)r) * LIN_IN + D_MODEL + lane * 8] = oe;
        *(bf16x8*)&vmb[((size_t)(N_REC + r)) * LIN_IN + D_MODEL + lane * 8] = oe;
    }
}

// ---------------------------------------------------------------------------
// Weight prep: w1t[n][k] = bf16(ff_w1[k][n]) (256x320),
//              w2t[n][k] = bf16(ff_w2[k][n]) (256x256)
__global__ __launch_bounds__(256) void prep_weights(
    const float* __restrict__ w1, const float* __restrict__ w2,
    unsigned short* __restrict__ w1t, unsigned short* __restrict__ w2t)
{
    const int tid = blockIdx.x * 256 + threadIdx.x;
    if (tid < 256 * LIN_IN) {
        const int n = tid / LIN_IN, k = tid - n * LIN_IN;
        w1t[tid] = f2bf(w1[k * LIN_OUT + n]);
    } else {
        const int t2 = tid - 256 * LIN_IN;
        if (t2 < 256 * 256) {
            const int n = t2 >> 8, k = t2 & 255;
            w2t[t2] = f2bf(w2[k * LIN_OUT + n]);
        }
    }
}

// ---------------------------------------------------------------------------
// m97-style node GEMM: C[M=131072 x 256] = A[M x K] * BT[256 x K]^T + bias.
// 128x256 tile, 8 waves (2 row x 4 col), BK=32, double-buffered LDS fed by
// global_load_lds(16B). LDS tiles are XOR-swizzled (slot ^= (row&3)^((row>>2)&3),
// an involution on bits 4-5 keyed by row bits) applied identically to the
// staged global SOURCE address and the ds_read address (both-sides rule).
// This makes each 16-lane quarter-wave's b128 reads hit 8 distinct 4-bank
// groups twice (2-way = free) instead of 8-way conflicts at 64B row stride.
// A-frag: lane(m=n16) k=kk+hi*8+j. B-frag: lane(n=n16) same k map. C/D:
// row=4*hi+reg, col=n16 within each 16x16 tile.
// L1 (K=320): writes h=relu(C) as bf16 IN-PLACE into vmb[row][0:256]
// (each block owns its 128 rows exclusively -> race-free).
// L2 (K=256): reads A=vmb[row][0:256], writes f32 out.
template<int K, bool IS_L1>
__global__ __launch_bounds__(512, 2) void gemm_node(
    const unsigned short* __restrict__ A,    // [M][*] stride LIN_IN shorts
    const unsigned short* __restrict__ BT,   // [256][K]
    const float* __restrict__ bias,          // [256]
    unsigned short* __restrict__ hout,       // L1: vmb (stride LIN_IN)
    float* __restrict__ fout)                // L2: out (stride 256)
{
    __shared__ __align__(16) char lds[49152];  // A: 2x8KB, B: 2x16KB

    const int tid  = threadIdx.x;
    const int lane = tid & 63, wave = tid >> 6;
    const int n16  = lane & 15, hi = lane >> 4;
    const int wr   = wave >> 2, wc = wave & 3;
    const size_t row0 = (size_t)blockIdx.x * GBM;

    // swizzled ds_read slot offset (f depends only on n16 since row bases are x16)
    const int f_l = (n16 & 3) ^ ((n16 >> 2) & 3);
    const int hsl = (hi ^ f_l) << 4;

    // stage K-chunk [kk, kk+32) into buffer `buf`
    auto stage = [&](int kk, int buf) {
        {   // A: 128 rows x 64B, one 16B issue/thread
            const int i = tid, row = i >> 2;
            const int sl = (i & 3) ^ ((row & 3) ^ ((row >> 2) & 3));
            const unsigned short* g = A + (row0 + row) * LIN_IN + kk + sl * 8;
            char* l = lds + (buf << 13) + ((tid >> 6) << 10);   // wave-uniform base
            async_copy16(l, g);
        }
#pragma unroll
        for (int p = 0; p < 2; ++p) {   // B: 256 rows x 64B, two issues/thread
            const int i = p * 512 + tid, row = i >> 2;
            const int sl = (i & 3) ^ ((row & 3) ^ ((row >> 2) & 3));
            const unsigned short* g = BT + (size_t)row * K + kk + sl * 8;
            char* l = lds + 16384 + (buf << 14) + (p << 13) + ((tid >> 6) << 10);
            async_copy16(l, g);
        }
    };

    f32x4 acc[4][4];
#pragma unroll
    for (int c = 0; c < 4; ++c) {
        const float bv = bias[64 * wc + 16 * c + n16];
#pragma unroll
        for (int t = 0; t < 4; ++t) {
            acc[t][c][0] = bv; acc[t][c][1] = bv; acc[t][c][2] = bv; acc[t][c][3] = bv;
        }
    }

    stage(0, 0);
    int cur = 0;
    const int NSTEP = K / 32;
    for (int step = 0; step < NSTEP; ++step) {
        if (step + 1 < NSTEP) stage((step + 1) * 32, cur ^ 1);
        __syncthreads();   // implicit vmcnt drain: buf `cur` staged & visible

        bf16x8 af[4], bf[4];
        const char* Ab = lds + (cur << 13);
        const char* Bb = lds + 16384 + (cur << 14);
#pragma unroll
        for (int t = 0; t < 4; ++t)
            af[t] = *(const bf16x8*)(Ab + (64 * wr + 16 * t + n16) * 64 + hsl);
#pragma unroll
        for (int c = 0; c < 4; ++c)
            bf[c] = *(const bf16x8*)(Bb + (64 * wc + 16 * c + n16) * 64 + hsl);
#pragma unroll
        for (int c = 0; c < 4; ++c)
#pragma unroll
            for (int t = 0; t < 4; ++t)
                acc[t][c] = __builtin_amdgcn_mfma_f32_16x16x32_bf16(af[t], bf[c], acc[t][c], 0, 0, 0);

        __syncthreads();   // protect buf `cur` before it is re-staged
        cur ^= 1;
    }

    if (IS_L1) {
#pragma unroll
        for (int t = 0; t < 4; ++t)
#pragma unroll
            for (int c = 0; c < 4; ++c)
#pragma unroll
                for (int r = 0; r < 4; ++r)
                    hout[(row0 + 64 * wr + 16 * t + 4 * hi + r) * LIN_IN + 64 * wc + 16 * c + n16] =
                        f2bf(fmaxf(acc[t][c][r], 0.0f));
    } else {
#pragma unroll
        for (int t = 0; t < 4; ++t)
#pragma unroll
            for (int c = 0; c < 4; ++c)
#pragma unroll
                for (int r = 0; r < 4; ++r)
                    fout[(row0 + 64 * wr + 16 * t + 4 * hi + r) * LIN_OUT + 64 * wc + 16 * c + n16] =
                        acc[t][c][r];
    }
}

// ---------------------------------------------------------------------------
extern "C" void kernel_launch(void* const* d_in, const int* in_sizes, int n_in,
                              void* d_out, int out_size, void* d_ws, size_t ws_size,
                              hipStream_t stream) {
    const float* x         = (const float*)d_in[0];
    const int*   edge_idx  = (const int*)d_in[1];
    const float* edge_attr = (const float*)d_in[2];
    const float* ee_w1     = (const float*)d_in[3];
    const float* ee_b1     = (const float*)d_in[4];
    const float* ee_w2     = (const float*)d_in[5];
    const float* ee_b2     = (const float*)d_in[6];
    const float* ff_w1     = (const float*)d_in[7];
    const float* ff_b1     = (const float*)d_in[8];
    const float* ff_w2     = (const float*)d_in[9];
    const float* ff_b2     = (const float*)d_in[10];
    float* out = (float*)d_out;

    const int* senders   = edge_idx;
    const int* receivers = edge_idx + N_EDGES;

    // Workspace layout (512B-aligned sub-buffers).
    char* ws = (char*)d_ws;
    size_t off = 0;
    auto alloc = [&](size_t bytes) { char* p = ws + off; off += (bytes + 511) & ~511ull; return p; };

    unsigned short* vmb = (unsigned short*)alloc((size_t)BATCH * N_REC * LIN_IN * 2);   // 83.9 MB
    unsigned short* efs = (unsigned short*)alloc((size_t)N_EDGES * EDGE_OUT * 2);       // 33.6 MB
    unsigned short* w1t = (unsigned short*)alloc((size_t)256 * LIN_IN * 2);
    unsigned short* w2t = (unsigned short*)alloc((size_t)256 * LIN_OUT * 2);
    int* row_ptr        = (int*)alloc((size_t)(N_REC + 1) * 4);
    int* counts         = (int*)alloc((size_t)N_REC * 4);
    int* cursor         = (int*)alloc((size_t)N_REC * 4);
    int* edge_order     = (int*)alloc((size_t)N_EDGES * 4);
    int* ssort          = (int*)alloc((size_t)N_EDGES * 4);
    const size_t base_need = off;
    unsigned short* xb  = (unsigned short*)(ws + off);
    const size_t xb_bytes = (size_t)BATCH * N_SEND * D_MODEL * 2;                        // 50.3 MB
    const bool use_xb = (ws_size >= base_need + xb_bytes);

    hipMemsetAsync(counts, 0, (size_t)N_REC * 4, stream);

    prep_weights<<<(256 * LIN_IN + 256 * LIN_OUT + 255) / 256, 256, 0, stream>>>(
        ff_w1, ff_w2, w1t, w2t);

    if (use_xb) {
        conv_x_kernel<<<(int)((size_t)BATCH * N_SEND * D_MODEL / 8 / 256), 256, 0, stream>>>(x, xb);
    }

    edge_mlp_kernel<<<N_EDGES / EPB, 256, 0, stream>>>(
        receivers, edge_attr, ee_w1, ee_b1, ee_w2, ee_b2, efs, counts);

    scan_kernel<<<1, 1024, 0, stream>>>(counts, row_ptr, cursor);

    fill_kernel<<<N_EDGES / 256, 256, 0, stream>>>(
        senders, receivers, cursor, edge_order, ssort);

    if (use_xb) {
        gather_kernel<true><<<N_REC / 4, 256, 0, stream>>>(
            x, xb, efs, row_ptr, edge_order, ssort, vmb);
    } else {
        gather_kernel<false><<<N_REC / 4, 256, 0, stream>>>(
            x, xb, efs, row_ptr, edge_order, ssort, vmb);
    }

    const int ngrid = (BATCH * N_REC) / GBM;   // 1024
    gemm_node<LIN_IN, true><<<ngrid, 512, 0, stream>>>(vmb, w1t, ff_b1, vmb, nullptr);
    gemm_node<LIN_OUT, false><<<ngrid, 512, 0, stream>>>(vmb, w2t, ff_b2, nullptr, out);
}

// Round 7
// 285.172 us; speedup vs baseline: 1.1393x; 1.0017x over previous
//
#include <hip/hip_runtime.h>
#include <hip/hip_bf16.h>

#define N_SEND 49152
#define N_REC  65536
#define N_EDGES 262144
#define D_MODEL 256
#define EDGE_IN 4
#define EDGE_OUT 64
#define LIN_IN 320
#define LIN_OUT 256
#define BATCH 2

#define EPB 32   // edges per block in edge MLP section
#define GBM 128  // rows per block in fused node GEMM

typedef __attribute__((ext_vector_type(4))) float f32x4;
typedef __attribute__((ext_vector_type(8))) short bf16x8;

static __device__ __forceinline__ unsigned short f2bf(float f) {
    union { float f; unsigned u; } v; v.f = f;
    unsigned r = v.u + 0x7FFF + ((v.u >> 16) & 1);   // round-to-nearest-even
    return (unsigned short)(r >> 16);
}
static __device__ __forceinline__ float bf2f(unsigned short h) {
    union { unsigned u; float f; } v; v.u = ((unsigned)h) << 16; return v.f;
}

// async global->LDS, 16B per lane; LDS dest = wave-uniform base + lane*16
static __device__ __forceinline__ void async_copy16(void* lds_ptr, const void* g_ptr) {
    __builtin_amdgcn_global_load_lds(
        (const __attribute__((address_space(1))) void*)g_ptr,
        (__attribute__((address_space(3))) void*)lds_ptr, 16, 0, 0);
}

// ---------------------------------------------------------------------------
// Fused prep: blockIdx ranges do [conv_x | edge MLP + histogram | weight prep].
// All three are independent; co-scheduling overlaps BW-bound conv with
// VALU-bound edge MLP and saves 2 kernel launches.
__global__ __launch_bounds__(256) void prep_fused(
    const float* __restrict__ x, unsigned short* __restrict__ xb, int nconv,
    const int* __restrict__ receivers, const float* __restrict__ edge_attr,
    const float* __restrict__ ee_w1, const float* __restrict__ ee_b1,
    const float* __restrict__ ee_w2, const float* __restrict__ ee_b2,
    unsigned short* __restrict__ efs, int* __restrict__ counts,
    const float* __restrict__ w1, const float* __restrict__ w2,
    unsigned short* __restrict__ w1t, unsigned short* __restrict__ w2t)
{
    __shared__ float h_lds[EPB][EDGE_OUT];
    __shared__ float e_lds[EPB][EDGE_OUT];

    const int bid = blockIdx.x;
    const int tid = threadIdx.x;

    // ---- section 1: x f32 -> xb bf16, 8 elems/thread ----
    if (bid < nconv) {
        const size_t i = ((size_t)bid * 256 + tid) * 8;
        const float4 v0 = *(const float4*)&x[i];
        const float4 v1 = *(const float4*)&x[i + 4];
        bf16x8 o;
        o[0] = (short)f2bf(v0.x); o[1] = (short)f2bf(v0.y);
        o[2] = (short)f2bf(v0.z); o[3] = (short)f2bf(v0.w);
        o[4] = (short)f2bf(v1.x); o[5] = (short)f2bf(v1.y);
        o[6] = (short)f2bf(v1.z); o[7] = (short)f2bf(v1.w);
        *(bf16x8*)&xb[i] = o;
        return;
    }
    const int b2 = bid - nconv;

    // ---- section 2: edge MLP (4->64 relu ->64) + receiver histogram ----
    if (b2 < N_EDGES / EPB) {
        const int e0 = b2 * EPB;

        if (tid < EPB) atomicAdd(&counts[receivers[e0 + tid]], 1);

        for (int i = tid; i < EPB * EDGE_OUT; i += 256) {
            const int e = i >> 6, j = i & 63;
            const float* ea = edge_attr + (size_t)(e0 + e) * EDGE_IN;
            float acc = ee_b1[j];
            acc += ea[0] * ee_w1[0 * EDGE_OUT + j];
            acc += ea[1] * ee_w1[1 * EDGE_OUT + j];
            acc += ea[2] * ee_w1[2 * EDGE_OUT + j];
            acc += ea[3] * ee_w1[3 * EDGE_OUT + j];
            h_lds[e][j] = fmaxf(acc, 0.0f);
        }
        __syncthreads();

        {
            const int j = tid & 63, g = tid >> 6;
            float acc[8];
#pragma unroll
            for (int e = 0; e < 8; ++e) acc[e] = ee_b2[j];
            for (int k = 0; k < EDGE_OUT; ++k) {
                const float w = ee_w2[k * EDGE_OUT + j];
#pragma unroll
                for (int e = 0; e < 8; ++e) acc[e] += h_lds[g * 8 + e][k] * w;
            }
#pragma unroll
            for (int e = 0; e < 8; ++e) e_lds[g * 8 + e][j] = acc[e];
        }
        __syncthreads();

        {
            const int e = tid >> 3, seg = tid & 7;
            const float* src = &e_lds[e][seg * 8];
            bf16x8 o;
#pragma unroll
            for (int j = 0; j < 8; ++j) o[j] = (short)f2bf(src[j]);
            *(bf16x8*)&efs[(size_t)(e0 + e) * EDGE_OUT + seg * 8] = o;
        }
        return;
    }

    // ---- section 3: weight transpose+convert ----
    {
        const int t3 = (b2 - N_EDGES / EPB) * 256 + tid;
        if (t3 < 256 * LIN_IN) {
            const int n = t3 / LIN_IN, k = t3 - n * LIN_IN;
            w1t[t3] = f2bf(w1[k * LIN_OUT + n]);
        } else {
            const int t2 = t3 - 256 * LIN_IN;
            if (t2 < 256 * 256) {
                const int n = t2 >> 8, k = t2 & 255;
                w2t[t2] = f2bf(w2[k * LIN_OUT + n]);
            }
        }
    }
}

// ---------------------------------------------------------------------------
// Exclusive scan of counts[65536] -> row_ptr[65537], copy to cursor.
__global__ __launch_bounds__(1024) void scan_kernel(
    const int* __restrict__ counts, int* __restrict__ row_ptr,
    int* __restrict__ cursor)
{
    __shared__ int sums[1024];
    const int t = threadIdx.x;
    const int4* c4 = (const int4*)(counts + t * 64);

    int s = 0;
#pragma unroll
    for (int i = 0; i < 16; ++i) { const int4 c = c4[i]; s += c.x + c.y + c.z + c.w; }
    sums[t] = s;
    __syncthreads();

    for (int off = 1; off < 1024; off <<= 1) {
        const int v = (t >= off) ? sums[t - off] : 0;
        __syncthreads();
        sums[t] += v;
        __syncthreads();
    }

    int run = sums[t] - s;
#pragma unroll
    for (int i = 0; i < 16; ++i) {
        const int4 c = c4[i];
        int4 w;
        w.x = run; w.y = run + c.x; w.z = w.y + c.y; w.w = w.z + c.z;
        run = w.w + c.w;
        ((int4*)(row_ptr + t * 64))[i] = w;
        ((int4*)(cursor + t * 64))[i] = w;
    }
    if (t == 1023) row_ptr[N_REC] = run;
}

// ---------------------------------------------------------------------------
// Bucket edges by receiver: edge_order[pos]=e, ssort[pos]=senders[e].
__global__ __launch_bounds__(256) void fill_kernel(
    const int* __restrict__ senders, const int* __restrict__ receivers,
    int* __restrict__ cursor, int* __restrict__ edge_order,
    int* __restrict__ ssort)
{
    const int e = blockIdx.x * 256 + threadIdx.x;
    const int r = receivers[e];
    const int pos = atomicAdd(&cursor[r], 1);
    edge_order[pos] = e;
    ssort[pos] = senders[e];
}

// ---------------------------------------------------------------------------
// Wave-per-receiver gather (unchanged).
template<bool XB>
__global__ __launch_bounds__(256) void gather_kernel(
    const float* __restrict__ x,
    const unsigned short* __restrict__ xb,
    const unsigned short* __restrict__ efs,
    const int* __restrict__ row_ptr,
    const int* __restrict__ edge_order,
    const int* __restrict__ ssort,
    unsigned short* __restrict__ vmb)
{
    const int lane = threadIdx.x & 63;
    const int wave = threadIdx.x >> 6;
    const int r = blockIdx.x * 4 + wave;
    const int beg = row_ptr[r], end = row_ptr[r + 1];
    const int half = lane >> 5, l2 = lane & 31;

    float ax[8] = {0, 0, 0, 0, 0, 0, 0, 0};
    float ae[8] = {0, 0, 0, 0, 0, 0, 0, 0};

    for (int chunk = beg; chunk < end; chunk += 64) {
        const int n = min(64, end - chunk);
        int myidx = 0, myeidx = 0;
        if (chunk + lane < end) {
            myidx = ssort[chunk + lane];
            myeidx = edge_order[chunk + lane];
        }
        for (int i = 0; i < n; ++i) {
            const int s = __shfl(myidx, i);
            const int e = __shfl(myeidx, i);
            const size_t rowbase = (size_t)(half ? N_SEND + s : s) * D_MODEL;
            if (XB) {
                const bf16x8 v = *(const bf16x8*)&xb[rowbase + l2 * 8];
#pragma unroll
                for (int j = 0; j < 8; ++j) ax[j] += bf2f((unsigned short)v[j]);
            } else {
                const float4 v0 = *(const float4*)&x[rowbase + l2 * 8];
                const float4 v1 = *(const float4*)&x[rowbase + l2 * 8 + 4];
                ax[0] += v0.x; ax[1] += v0.y; ax[2] += v0.z; ax[3] += v0.w;
                ax[4] += v1.x; ax[5] += v1.y; ax[6] += v1.z; ax[7] += v1.w;
            }
            if (lane < 8) {
                const bf16x8 w = *(const bf16x8*)&efs[(size_t)e * EDGE_OUT + lane * 8];
#pragma unroll
                for (int j = 0; j < 8; ++j) ae[j] += bf2f((unsigned short)w[j]);
            }
        }
    }

    bf16x8 o;
#pragma unroll
    for (int j = 0; j < 8; ++j) o[j] = (short)f2bf(ax[j]);
    *(bf16x8*)&vmb[((size_t)(half * N_REC + r)) * LIN_IN + l2 * 8] = o;
    if (lane < 8) {
        bf16x8 oe;
#pragma unroll
        for (int j = 0; j < 8; ++j) oe[j] = (short)f2bf(ae[j]);
        *(bf16x8*)&vmb[((size_t)r) * LIN_IN + D_MODEL + lane * 8] = oe;
        *(bf16x8*)&vmb[((size_t)(N_REC + r)) * LIN_IN + D_MODEL + lane * 8] = oe;
    }
}

// ---------------------------------------------------------------------------
// Fused node MLP: out = relu(vm @ w1 + b1) @ w2 + b2 in ONE kernel.
// 128x256 tile, 8 waves (2x4), BK=32, global_load_lds dbuf staging with the
// proven XOR slot swizzle (both-sides involution, round-6 verified).
// Layer 1 (K=320) accumulates, then h=relu is written (bf16) into LDS in the
// SAME wire-format stage() produces: [8 kchunks][128 rows][64B], element at
// global slot g stored at LDS slot g^f(row), f(row)=(row&3)^((row>>2)&3).
// Layer 2 (K=256) reads A-fragments from h_lds via the identical hsl path and
// stages only the w2t panel (2x16KB dbuf). Saves the 134MB h HBM round-trip.
// LDS: A-stage 16KB + B-stage 32KB + h 64KB = 112KB -> 1 block/CU.
__global__ __launch_bounds__(512, 1) void node_mlp_fused(
    const unsigned short* __restrict__ vmb,   // [2*N_REC][320] bf16
    const unsigned short* __restrict__ w1t,   // [256][320] bf16
    const float* __restrict__ b1,
    const unsigned short* __restrict__ w2t,   // [256][256] bf16
    const float* __restrict__ b2,
    float* __restrict__ out)
{
    __shared__ __align__(16) char lds[114688];
    // [0,16384): A dbuf 2x8KB | [16384,49152): B dbuf 2x16KB | [49152,+65536): h

    const int tid  = threadIdx.x;
    const int lane = tid & 63, wave = tid >> 6;
    const int n16  = lane & 15, hi = lane >> 4;
    const int wr   = wave >> 2, wc = wave & 3;
    const size_t row0 = (size_t)blockIdx.x * GBM;
    char* const hbase = lds + 49152;

    const int f_l = (n16 & 3) ^ ((n16 >> 2) & 3);
    const int hsl = (hi ^ f_l) << 4;

    auto stageA = [&](int kk, int buf) {
        const int row = tid >> 2;
        const int sl = (tid & 3) ^ ((row & 3) ^ ((row >> 2) & 3));
        const unsigned short* g = vmb + (row0 + row) * LIN_IN + kk + sl * 8;
        char* l = lds + (buf << 13) + ((tid >> 6) << 10);
        async_copy16(l, g);
    };
    auto stageB = [&](const unsigned short* BT, int ldk, int kk, int buf) {
#pragma unroll
        for (int p = 0; p < 2; ++p) {
            const int i = p * 512 + tid, row = i >> 2;
            const int sl = (i & 3) ^ ((row & 3) ^ ((row >> 2) & 3));
            const unsigned short* g = BT + (size_t)row * ldk + kk + sl * 8;
            char* l = lds + 16384 + (buf << 14) + (p << 13) + ((tid >> 6) << 10);
            async_copy16(l, g);
        }
    };

    // ---- Layer 1: K=320, 10 steps ----
    f32x4 acc[4][4];
#pragma unroll
    for (int c = 0; c < 4; ++c) {
        const float bv = b1[64 * wc + 16 * c + n16];
#pragma unroll
        for (int t = 0; t < 4; ++t) {
            acc[t][c][0] = bv; acc[t][c][1] = bv; acc[t][c][2] = bv; acc[t][c][3] = bv;
        }
    }

    stageA(0, 0); stageB(w1t, LIN_IN, 0, 0);
    int cur = 0;
    for (int step = 0; step < LIN_IN / 32; ++step) {
        if (step + 1 < LIN_IN / 32) {
            stageA((step + 1) * 32, cur ^ 1);
            stageB(w1t, LIN_IN, (step + 1) * 32, cur ^ 1);
        }
        __syncthreads();   // buf `cur` staged & visible (vmcnt drained)

        bf16x8 af[4], bf[4];
        const char* Ab = lds + (cur << 13);
        const char* Bb = lds + 16384 + (cur << 14);
#pragma unroll
        for (int t = 0; t < 4; ++t)
            af[t] = *(const bf16x8*)(Ab + (64 * wr + 16 * t + n16) * 64 + hsl);
#pragma unroll
        for (int c = 0; c < 4; ++c)
            bf[c] = *(const bf16x8*)(Bb + (64 * wc + 16 * c + n16) * 64 + hsl);
#pragma unroll
        for (int c = 0; c < 4; ++c)
#pragma unroll
            for (int t = 0; t < 4; ++t)
                acc[t][c] = __builtin_amdgcn_mfma_f32_16x16x32_bf16(af[t], bf[c], acc[t][c], 0, 0, 0);

        __syncthreads();   // protect buf `cur` before re-stage
        cur ^= 1;
    }

    // ---- h = relu(acc) -> LDS in stage wire-format ----
    // C/D: local row = 64wr + 16t + 4hi + r, col = 64wc + 16c + n16.
#pragma unroll
    for (int t = 0; t < 4; ++t)
#pragma unroll
        for (int c = 0; c < 4; ++c) {
            const int col = 64 * wc + 16 * c + n16;
            const int kc = col >> 5;
            const int b  = (col & 31) * 2;      // byte within 64B row segment
            const int gslot = b >> 4;
#pragma unroll
            for (int r = 0; r < 4; ++r) {
                const int lrow = 64 * wr + 16 * t + 4 * hi + r;
                const int f = (lrow & 3) ^ ((lrow >> 2) & 3);
                *(unsigned short*)(hbase + (kc << 13) + lrow * 64 + (((gslot ^ f) << 4) | (b & 15))) =
                    f2bf(fmaxf(acc[t][c][r], 0.0f));
            }
        }
    __syncthreads();   // h visible to all waves

    // ---- Layer 2: K=256, 8 steps; A from h_lds, B staged ----
    f32x4 acc2[4][4];
#pragma unroll
    for (int c = 0; c < 4; ++c) {
        const float bv = b2[64 * wc + 16 * c + n16];
#pragma unroll
        for (int t = 0; t < 4; ++t) {
            acc2[t][c][0] = bv; acc2[t][c][1] = bv; acc2[t][c][2] = bv; acc2[t][c][3] = bv;
        }
    }

    stageB(w2t, LIN_OUT, 0, 0);
    cur = 0;
    for (int step = 0; step < LIN_OUT / 32; ++step) {
        if (step + 1 < LIN_OUT / 32) stageB(w2t, LIN_OUT, (step + 1) * 32, cur ^ 1);
        __syncthreads();

        bf16x8 af[4], bf[4];
        const char* Hb = hbase + (step << 13);
        const char* Bb = lds + 16384 + (cur << 14);
#pragma unroll
        for (int t = 0; t < 4; ++t)
            af[t] = *(const bf16x8*)(Hb + (64 * wr + 16 * t + n16) * 64 + hsl);
#pragma unroll
        for (int c = 0; c < 4; ++c)
            bf[c] = *(const bf16x8*)(Bb + (64 * wc + 16 * c + n16) * 64 + hsl);
#pragma unroll
        for (int c = 0; c < 4; ++c)
#pragma unroll
            for (int t = 0; t < 4; ++t)
                acc2[t][c] = __builtin_amdgcn_mfma_f32_16x16x32_bf16(af[t], bf[c], acc2[t][c], 0, 0, 0);

        __syncthreads();
        cur ^= 1;
    }

#pragma unroll
    for (int t = 0; t < 4; ++t)
#pragma unroll
        for (int c = 0; c < 4; ++c)
#pragma unroll
            for (int r = 0; r < 4; ++r)
                out[(row0 + 64 * wr + 16 * t + 4 * hi + r) * LIN_OUT + 64 * wc + 16 * c + n16] =
                    acc2[t][c][r];
}

// ---------------------------------------------------------------------------
extern "C" void kernel_launch(void* const* d_in, const int* in_sizes, int n_in,
                              void* d_out, int out_size, void* d_ws, size_t ws_size,
                              hipStream_t stream) {
    const float* x         = (const float*)d_in[0];
    const int*   edge_idx  = (const int*)d_in[1];
    const float* edge_attr = (const float*)d_in[2];
    const float* ee_w1     = (const float*)d_in[3];
    const float* ee_b1     = (const float*)d_in[4];
    const float* ee_w2     = (const float*)d_in[5];
    const float* ee_b2     = (const float*)d_in[6];
    const float* ff_w1     = (const float*)d_in[7];
    const float* ff_b1     = (const float*)d_in[8];
    const float* ff_w2     = (const float*)d_in[9];
    const float* ff_b2     = (const float*)d_in[10];
    float* out = (float*)d_out;

    const int* senders   = edge_idx;
    const int* receivers = edge_idx + N_EDGES;

    // Workspace layout (512B-aligned sub-buffers).
    char* ws = (char*)d_ws;
    size_t off = 0;
    auto alloc = [&](size_t bytes) { char* p = ws + off; off += (bytes + 511) & ~511ull; return p; };

    unsigned short* vmb = (unsigned short*)alloc((size_t)BATCH * N_REC * LIN_IN * 2);   // 83.9 MB
    unsigned short* efs = (unsigned short*)alloc((size_t)N_EDGES * EDGE_OUT * 2);       // 33.6 MB
    unsigned short* w1t = (unsigned short*)alloc((size_t)256 * LIN_IN * 2);
    unsigned short* w2t = (unsigned short*)alloc((size_t)256 * LIN_OUT * 2);
    int* row_ptr        = (int*)alloc((size_t)(N_REC + 1) * 4);
    int* counts         = (int*)alloc((size_t)N_REC * 4);
    int* cursor         = (int*)alloc((size_t)N_REC * 4);
    int* edge_order     = (int*)alloc((size_t)N_EDGES * 4);
    int* ssort          = (int*)alloc((size_t)N_EDGES * 4);
    const size_t base_need = off;
    unsigned short* xb  = (unsigned short*)(ws + off);
    const size_t xb_bytes = (size_t)BATCH * N_SEND * D_MODEL * 2;                        // 50.3 MB
    const bool use_xb = (ws_size >= base_need + xb_bytes);

    hipMemsetAsync(counts, 0, (size_t)N_REC * 4, stream);

    const int nconv = use_xb ? (int)((size_t)BATCH * N_SEND * D_MODEL / 8 / 256) : 0;  // 12288
    const int prep_grid = nconv + N_EDGES / EPB + (256 * LIN_IN + 256 * LIN_OUT + 255) / 256;
    prep_fused<<<prep_grid, 256, 0, stream>>>(
        x, xb, nconv, receivers, edge_attr, ee_w1, ee_b1, ee_w2, ee_b2,
        efs, counts, ff_w1, ff_w2, w1t, w2t);

    scan_kernel<<<1, 1024, 0, stream>>>(counts, row_ptr, cursor);

    fill_kernel<<<N_EDGES / 256, 256, 0, stream>>>(
        senders, receivers, cursor, edge_order, ssort);

    if (use_xb) {
        gather_kernel<true><<<N_REC / 4, 256, 0, stream>>>(
            x, xb, efs, row_ptr, edge_order, ssort, vmb);
    } else {
        gather_kernel<false><<<N_REC / 4, 256, 0, stream>>>(
            x, xb, efs, row_ptr, edge_order, ssort, vmb);
    }

    node_mlp_fused<<<(BATCH * N_REC) / GBM, 512, 0, stream>>>(
        vmb, w1t, ff_b1, w2t, ff_b2, out);
}

// Round 8
// 251.980 us; speedup vs baseline: 1.2894x; 1.1317x over previous
//
#include <hip/hip_runtime.h>
#include <hip/hip_bf16.h>

#define N_SEND 49152
#define N_REC  65536
#define N_EDGES 262144
#define D_MODEL 256
#define EDGE_IN 4
#define EDGE_OUT 64
#define LIN_IN 320
#define LIN_OUT 256
#define BATCH 2

#define GBM 128  // rows per block in fused node GEMM

typedef __attribute__((ext_vector_type(4))) float f32x4;
typedef __attribute__((ext_vector_type(8))) short bf16x8;

static __device__ __forceinline__ unsigned short f2bf(float f) {
    union { float f; unsigned u; } v; v.f = f;
    unsigned r = v.u + 0x7FFF + ((v.u >> 16) & 1);   // round-to-nearest-even
    return (unsigned short)(r >> 16);
}
static __device__ __forceinline__ float bf2f(unsigned short h) {
    union { unsigned u; float f; } v; v.u = ((unsigned)h) << 16; return v.f;
}

// async global->LDS, 16B per lane; LDS dest = wave-uniform base + lane*16
static __device__ __forceinline__ void async_copy16(void* lds_ptr, const void* g_ptr) {
    __builtin_amdgcn_global_load_lds(
        (const __attribute__((address_space(1))) void*)g_ptr,
        (__attribute__((address_space(3))) void*)lds_ptr, 16, 0, 0);
}

// ---------------------------------------------------------------------------
// Fused prep: blockIdx ranges do [conv_x | edge MLP (MFMA) + histogram |
// weight prep]. Independent sections co-scheduled.
// Edge MLP section: 256 edges/block, 4 waves x 64 edges. Phase A: h=relu(
// ea@W1+b1) via 4 FMAs/output, written bf16 to LDS with XOR slot swizzle
// (slot ^= row&7; write- and read-side both computed -> T2-legal, 2-way free).
// Phase B: ef = h@W2+b2 on MFMA; A-frags from own-wave LDS rows (no barrier
// needed -- same-wave ds ordering), B-frags from L2-hot ee_w2 (f32->bf16).
__global__ __launch_bounds__(256) void prep_fused(
    const float* __restrict__ x, unsigned short* __restrict__ xb, int nconv,
    const int* __restrict__ receivers, const float* __restrict__ edge_attr,
    const float* __restrict__ ee_w1, const float* __restrict__ ee_b1,
    const float* __restrict__ ee_w2, const float* __restrict__ ee_b2,
    unsigned short* __restrict__ efs, int* __restrict__ counts,
    const float* __restrict__ w1, const float* __restrict__ w2,
    unsigned short* __restrict__ w1t, unsigned short* __restrict__ w2t)
{
    __shared__ __align__(16) unsigned short h_lds[256 * EDGE_OUT];   // 32 KB

    const int bid = blockIdx.x;
    const int tid = threadIdx.x;

    // ---- section 1: x f32 -> xb bf16, 8 elems/thread ----
    if (bid < nconv) {
        const size_t i = ((size_t)bid * 256 + tid) * 8;
        const float4 v0 = *(const float4*)&x[i];
        const float4 v1 = *(const float4*)&x[i + 4];
        bf16x8 o;
        o[0] = (short)f2bf(v0.x); o[1] = (short)f2bf(v0.y);
        o[2] = (short)f2bf(v0.z); o[3] = (short)f2bf(v0.w);
        o[4] = (short)f2bf(v1.x); o[5] = (short)f2bf(v1.y);
        o[6] = (short)f2bf(v1.z); o[7] = (short)f2bf(v1.w);
        *(bf16x8*)&xb[i] = o;
        return;
    }
    const int b2 = bid - nconv;

    // ---- section 2: edge MLP (4->64 relu ->64) on MFMA + histogram ----
    if (b2 < N_EDGES / 256) {
        const int e0 = b2 * 256;
        atomicAdd(&counts[receivers[e0 + tid]], 1);

        // Phase A: thread owns edge e0+tid; 64 outputs, packed bf16x8 writes.
        {
            const float4 ea = *(const float4*)&edge_attr[(size_t)(e0 + tid) * EDGE_IN];
#pragma unroll
            for (int kb = 0; kb < 8; ++kb) {
                bf16x8 hv;
#pragma unroll
                for (int j = 0; j < 8; ++j) {
                    const int k = kb * 8 + j;
                    float a = ee_b1[k];
                    a += ea.x * ee_w1[0 * EDGE_OUT + k];
                    a += ea.y * ee_w1[1 * EDGE_OUT + k];
                    a += ea.z * ee_w1[2 * EDGE_OUT + k];
                    a += ea.w * ee_w1[3 * EDGE_OUT + k];
                    hv[j] = (short)f2bf(fmaxf(a, 0.0f));
                }
                h_lds[tid * EDGE_OUT + ((kb ^ (tid & 7)) * 8)] = 0;  // placate none
                *(bf16x8*)&h_lds[tid * EDGE_OUT + ((kb ^ (tid & 7)) * 8)] = hv;
            }
        }

        // Phase B: ef = h @ W2 + b2 via mfma_16x16x32. Wave w: edges
        // [64w,64w+64). A-frag: lane(m=16t+n16) k=32ch+8hi+j (own-wave rows).
        const int lane = tid & 63, wave = tid >> 6;
        const int n16 = lane & 15, hi = lane >> 4;

        bf16x8 bfr[2][4];
#pragma unroll
        for (int ch = 0; ch < 2; ++ch)
#pragma unroll
            for (int c = 0; c < 4; ++c) {
                bf16x8 b;
#pragma unroll
                for (int j = 0; j < 8; ++j) {
                    const int k = ch * 32 + hi * 8 + j;
                    b[j] = (short)f2bf(ee_w2[k * EDGE_OUT + 16 * c + n16]);
                }
                bfr[ch][c] = b;
            }

        f32x4 acc[4][4];
#pragma unroll
        for (int c = 0; c < 4; ++c) {
            const float bv = ee_b2[16 * c + n16];
#pragma unroll
            for (int t = 0; t < 4; ++t) {
                acc[t][c][0] = bv; acc[t][c][1] = bv; acc[t][c][2] = bv; acc[t][c][3] = bv;
            }
        }

#pragma unroll
        for (int ch = 0; ch < 2; ++ch) {
            bf16x8 af[4];
#pragma unroll
            for (int t = 0; t < 4; ++t) {
                const int row = 64 * wave + 16 * t + n16;
                const int slot = (4 * ch + hi) ^ (row & 7);
                af[t] = *(const bf16x8*)&h_lds[row * EDGE_OUT + slot * 8];
            }
#pragma unroll
            for (int c = 0; c < 4; ++c)
#pragma unroll
                for (int t = 0; t < 4; ++t)
                    acc[t][c] = __builtin_amdgcn_mfma_f32_16x16x32_bf16(af[t], bfr[ch][c], acc[t][c], 0, 0, 0);
        }

        // C/D: edge = e0 + 64w + 16t + 4hi + r, col = 16c + n16.
#pragma unroll
        for (int t = 0; t < 4; ++t)
#pragma unroll
            for (int c = 0; c < 4; ++c)
#pragma unroll
                for (int r = 0; r < 4; ++r)
                    efs[(size_t)(e0 + 64 * wave + 16 * t + 4 * hi + r) * EDGE_OUT + 16 * c + n16] =
                        f2bf(acc[t][c][r]);
        return;
    }

    // ---- section 3: weight transpose+convert ----
    {
        const int t3 = (b2 - N_EDGES / 256) * 256 + tid;
        if (t3 < 256 * LIN_IN) {
            const int n = t3 / LIN_IN, k = t3 - n * LIN_IN;
            w1t[t3] = f2bf(w1[k * LIN_OUT + n]);
        } else {
            const int t2 = t3 - 256 * LIN_IN;
            if (t2 < 256 * 256) {
                const int n = t2 >> 8, k = t2 & 255;
                w2t[t2] = f2bf(w2[k * LIN_OUT + n]);
            }
        }
    }
}

// ---------------------------------------------------------------------------
// Exclusive scan of counts[65536] -> row_ptr[65537], copy to cursor.
__global__ __launch_bounds__(1024) void scan_kernel(
    const int* __restrict__ counts, int* __restrict__ row_ptr,
    int* __restrict__ cursor)
{
    __shared__ int sums[1024];
    const int t = threadIdx.x;
    const int4* c4 = (const int4*)(counts + t * 64);

    int s = 0;
#pragma unroll
    for (int i = 0; i < 16; ++i) { const int4 c = c4[i]; s += c.x + c.y + c.z + c.w; }
    sums[t] = s;
    __syncthreads();

    for (int off = 1; off < 1024; off <<= 1) {
        const int v = (t >= off) ? sums[t - off] : 0;
        __syncthreads();
        sums[t] += v;
        __syncthreads();
    }

    int run = sums[t] - s;
#pragma unroll
    for (int i = 0; i < 16; ++i) {
        const int4 c = c4[i];
        int4 w;
        w.x = run; w.y = run + c.x; w.z = w.y + c.y; w.w = w.z + c.z;
        run = w.w + c.w;
        ((int4*)(row_ptr + t * 64))[i] = w;
        ((int4*)(cursor + t * 64))[i] = w;
    }
    if (t == 1023) row_ptr[N_REC] = run;
}

// ---------------------------------------------------------------------------
// Bucket edges by receiver: edge_order[pos]=e, ssort[pos]=senders[e].
__global__ __launch_bounds__(256) void fill_kernel(
    const int* __restrict__ senders, const int* __restrict__ receivers,
    int* __restrict__ cursor, int* __restrict__ edge_order,
    int* __restrict__ ssort)
{
    const int e = blockIdx.x * 256 + threadIdx.x;
    const int r = receivers[e];
    const int pos = atomicAdd(&cursor[r], 1);
    edge_order[pos] = e;
    ssort[pos] = senders[e];
}

// ---------------------------------------------------------------------------
// Wave-per-receiver gather (unchanged).
template<bool XB>
__global__ __launch_bounds__(256) void gather_kernel(
    const float* __restrict__ x,
    const unsigned short* __restrict__ xb,
    const unsigned short* __restrict__ efs,
    const int* __restrict__ row_ptr,
    const int* __restrict__ edge_order,
    const int* __restrict__ ssort,
    unsigned short* __restrict__ vmb)
{
    const int lane = threadIdx.x & 63;
    const int wave = threadIdx.x >> 6;
    const int r = blockIdx.x * 4 + wave;
    const int beg = row_ptr[r], end = row_ptr[r + 1];
    const int half = lane >> 5, l2 = lane & 31;

    float ax[8] = {0, 0, 0, 0, 0, 0, 0, 0};
    float ae[8] = {0, 0, 0, 0, 0, 0, 0, 0};

    for (int chunk = beg; chunk < end; chunk += 64) {
        const int n = min(64, end - chunk);
        int myidx = 0, myeidx = 0;
        if (chunk + lane < end) {
            myidx = ssort[chunk + lane];
            myeidx = edge_order[chunk + lane];
        }
        for (int i = 0; i < n; ++i) {
            const int s = __shfl(myidx, i);
            const int e = __shfl(myeidx, i);
            const size_t rowbase = (size_t)(half ? N_SEND + s : s) * D_MODEL;
            if (XB) {
                const bf16x8 v = *(const bf16x8*)&xb[rowbase + l2 * 8];
#pragma unroll
                for (int j = 0; j < 8; ++j) ax[j] += bf2f((unsigned short)v[j]);
            } else {
                const float4 v0 = *(const float4*)&x[rowbase + l2 * 8];
                const float4 v1 = *(const float4*)&x[rowbase + l2 * 8 + 4];
                ax[0] += v0.x; ax[1] += v0.y; ax[2] += v0.z; ax[3] += v0.w;
                ax[4] += v1.x; ax[5] += v1.y; ax[6] += v1.z; ax[7] += v1.w;
            }
            if (lane < 8) {
                const bf16x8 w = *(const bf16x8*)&efs[(size_t)e * EDGE_OUT + lane * 8];
#pragma unroll
                for (int j = 0; j < 8; ++j) ae[j] += bf2f((unsigned short)w[j]);
            }
        }
    }

    bf16x8 o;
#pragma unroll
    for (int j = 0; j < 8; ++j) o[j] = (short)f2bf(ax[j]);
    *(bf16x8*)&vmb[((size_t)(half * N_REC + r)) * LIN_IN + l2 * 8] = o;
    if (lane < 8) {
        bf16x8 oe;
#pragma unroll
        for (int j = 0; j < 8; ++j) oe[j] = (short)f2bf(ae[j]);
        *(bf16x8*)&vmb[((size_t)r) * LIN_IN + D_MODEL + lane * 8] = oe;
        *(bf16x8*)&vmb[((size_t)(N_REC + r)) * LIN_IN + D_MODEL + lane * 8] = oe;
    }
}

// ---------------------------------------------------------------------------
// Fused node MLP (unchanged from round 7).
__global__ __launch_bounds__(512, 1) void node_mlp_fused(
    const unsigned short* __restrict__ vmb,   // [2*N_REC][320] bf16
    const unsigned short* __restrict__ w1t,   // [256][320] bf16
    const float* __restrict__ b1,
    const unsigned short* __restrict__ w2t,   // [256][256] bf16
    const float* __restrict__ b2,
    float* __restrict__ out)
{
    __shared__ __align__(16) char lds[114688];
    // [0,16384): A dbuf 2x8KB | [16384,49152): B dbuf 2x16KB | [49152,+65536): h

    const int tid  = threadIdx.x;
    const int lane = tid & 63, wave = tid >> 6;
    const int n16  = lane & 15, hi = lane >> 4;
    const int wr   = wave >> 2, wc = wave & 3;
    const size_t row0 = (size_t)blockIdx.x * GBM;
    char* const hbase = lds + 49152;

    const int f_l = (n16 & 3) ^ ((n16 >> 2) & 3);
    const int hsl = (hi ^ f_l) << 4;

    auto stageA = [&](int kk, int buf) {
        const int row = tid >> 2;
        const int sl = (tid & 3) ^ ((row & 3) ^ ((row >> 2) & 3));
        const unsigned short* g = vmb + (row0 + row) * LIN_IN + kk + sl * 8;
        char* l = lds + (buf << 13) + ((tid >> 6) << 10);
        async_copy16(l, g);
    };
    auto stageB = [&](const unsigned short* BT, int ldk, int kk, int buf) {
#pragma unroll
        for (int p = 0; p < 2; ++p) {
            const int i = p * 512 + tid, row = i >> 2;
            const int sl = (i & 3) ^ ((row & 3) ^ ((row >> 2) & 3));
            const unsigned short* g = BT + (size_t)row * ldk + kk + sl * 8;
            char* l = lds + 16384 + (buf << 14) + (p << 13) + ((tid >> 6) << 10);
            async_copy16(l, g);
        }
    };

    // ---- Layer 1: K=320, 10 steps ----
    f32x4 acc[4][4];
#pragma unroll
    for (int c = 0; c < 4; ++c) {
        const float bv = b1[64 * wc + 16 * c + n16];
#pragma unroll
        for (int t = 0; t < 4; ++t) {
            acc[t][c][0] = bv; acc[t][c][1] = bv; acc[t][c][2] = bv; acc[t][c][3] = bv;
        }
    }

    stageA(0, 0); stageB(w1t, LIN_IN, 0, 0);
    int cur = 0;
    for (int step = 0; step < LIN_IN / 32; ++step) {
        if (step + 1 < LIN_IN / 32) {
            stageA((step + 1) * 32, cur ^ 1);
            stageB(w1t, LIN_IN, (step + 1) * 32, cur ^ 1);
        }
        __syncthreads();   // buf `cur` staged & visible (vmcnt drained)

        bf16x8 af[4], bf[4];
        const char* Ab = lds + (cur << 13);
        const char* Bb = lds + 16384 + (cur << 14);
#pragma unroll
        for (int t = 0; t < 4; ++t)
            af[t] = *(const bf16x8*)(Ab + (64 * wr + 16 * t + n16) * 64 + hsl);
#pragma unroll
        for (int c = 0; c < 4; ++c)
            bf[c] = *(const bf16x8*)(Bb + (64 * wc + 16 * c + n16) * 64 + hsl);
#pragma unroll
        for (int c = 0; c < 4; ++c)
#pragma unroll
            for (int t = 0; t < 4; ++t)
                acc[t][c] = __builtin_amdgcn_mfma_f32_16x16x32_bf16(af[t], bf[c], acc[t][c], 0, 0, 0);

        __syncthreads();   // protect buf `cur` before re-stage
        cur ^= 1;
    }

    // ---- h = relu(acc) -> LDS in stage wire-format ----
#pragma unroll
    for (int t = 0; t < 4; ++t)
#pragma unroll
        for (int c = 0; c < 4; ++c) {
            const int col = 64 * wc + 16 * c + n16;
            const int kc = col >> 5;
            const int b  = (col & 31) * 2;      // byte within 64B row segment
            const int gslot = b >> 4;
#pragma unroll
            for (int r = 0; r < 4; ++r) {
                const int lrow = 64 * wr + 16 * t + 4 * hi + r;
                const int f = (lrow & 3) ^ ((lrow >> 2) & 3);
                *(unsigned short*)(hbase + (kc << 13) + lrow * 64 + (((gslot ^ f) << 4) | (b & 15))) =
                    f2bf(fmaxf(acc[t][c][r], 0.0f));
            }
        }
    __syncthreads();   // h visible to all waves

    // ---- Layer 2: K=256, 8 steps; A from h_lds, B staged ----
    f32x4 acc2[4][4];
#pragma unroll
    for (int c = 0; c < 4; ++c) {
        const float bv = b2[64 * wc + 16 * c + n16];
#pragma unroll
        for (int t = 0; t < 4; ++t) {
            acc2[t][c][0] = bv; acc2[t][c][1] = bv; acc2[t][c][2] = bv; acc2[t][c][3] = bv;
        }
    }

    stageB(w2t, LIN_OUT, 0, 0);
    cur = 0;
    for (int step = 0; step < LIN_OUT / 32; ++step) {
        if (step + 1 < LIN_OUT / 32) stageB(w2t, LIN_OUT, (step + 1) * 32, cur ^ 1);
        __syncthreads();

        bf16x8 af[4], bf[4];
        const char* Hb = hbase + (step << 13);
        const char* Bb = lds + 16384 + (cur << 14);
#pragma unroll
        for (int t = 0; t < 4; ++t)
            af[t] = *(const bf16x8*)(Hb + (64 * wr + 16 * t + n16) * 64 + hsl);
#pragma unroll
        for (int c = 0; c < 4; ++c)
            bf[c] = *(const bf16x8*)(Bb + (64 * wc + 16 * c + n16) * 64 + hsl);
#pragma unroll
        for (int c = 0; c < 4; ++c)
#pragma unroll
            for (int t = 0; t < 4; ++t)
                acc2[t][c] = __builtin_amdgcn_mfma_f32_16x16x32_bf16(af[t], bf[c], acc2[t][c], 0, 0, 0);

        __syncthreads();
        cur ^= 1;
    }

#pragma unroll
    for (int t = 0; t < 4; ++t)
#pragma unroll
        for (int c = 0; c < 4; ++c)
#pragma unroll
            for (int r = 0; r < 4; ++r)
                out[(row0 + 64 * wr + 16 * t + 4 * hi + r) * LIN_OUT + 64 * wc + 16 * c + n16] =
                    acc2[t][c][r];
}

// ---------------------------------------------------------------------------
extern "C" void kernel_launch(void* const* d_in, const int* in_sizes, int n_in,
                              void* d_out, int out_size, void* d_ws, size_t ws_size,
                              hipStream_t stream) {
    const float* x         = (const float*)d_in[0];
    const int*   edge_idx  = (const int*)d_in[1];
    const float* edge_attr = (const float*)d_in[2];
    const float* ee_w1     = (const float*)d_in[3];
    const float* ee_b1     = (const float*)d_in[4];
    const float* ee_w2     = (const float*)d_in[5];
    const float* ee_b2     = (const float*)d_in[6];
    const float* ff_w1     = (const float*)d_in[7];
    const float* ff_b1     = (const float*)d_in[8];
    const float* ff_w2     = (const float*)d_in[9];
    const float* ff_b2     = (const float*)d_in[10];
    float* out = (float*)d_out;

    const int* senders   = edge_idx;
    const int* receivers = edge_idx + N_EDGES;

    // Workspace layout (512B-aligned sub-buffers).
    char* ws = (char*)d_ws;
    size_t off = 0;
    auto alloc = [&](size_t bytes) { char* p = ws + off; off += (bytes + 511) & ~511ull; return p; };

    unsigned short* vmb = (unsigned short*)alloc((size_t)BATCH * N_REC * LIN_IN * 2);   // 83.9 MB
    unsigned short* efs = (unsigned short*)alloc((size_t)N_EDGES * EDGE_OUT * 2);       // 33.6 MB
    unsigned short* w1t = (unsigned short*)alloc((size_t)256 * LIN_IN * 2);
    unsigned short* w2t = (unsigned short*)alloc((size_t)256 * LIN_OUT * 2);
    int* row_ptr        = (int*)alloc((size_t)(N_REC + 1) * 4);
    int* counts         = (int*)alloc((size_t)N_REC * 4);
    int* cursor         = (int*)alloc((size_t)N_REC * 4);
    int* edge_order     = (int*)alloc((size_t)N_EDGES * 4);
    int* ssort          = (int*)alloc((size_t)N_EDGES * 4);
    const size_t base_need = off;
    unsigned short* xb  = (unsigned short*)(ws + off);
    const size_t xb_bytes = (size_t)BATCH * N_SEND * D_MODEL * 2;                        // 50.3 MB
    const bool use_xb = (ws_size >= base_need + xb_bytes);

    hipMemsetAsync(counts, 0, (size_t)N_REC * 4, stream);

    const int nconv = use_xb ? (int)((size_t)BATCH * N_SEND * D_MODEL / 8 / 256) : 0;  // 12288
    const int prep_grid = nconv + N_EDGES / 256 + (256 * LIN_IN + 256 * LIN_OUT + 255) / 256;
    prep_fused<<<prep_grid, 256, 0, stream>>>(
        x, xb, nconv, receivers, edge_attr, ee_w1, ee_b1, ee_w2, ee_b2,
        efs, counts, ff_w1, ff_w2, w1t, w2t);

    scan_kernel<<<1, 1024, 0, stream>>>(counts, row_ptr, cursor);

    fill_kernel<<<N_EDGES / 256, 256, 0, stream>>>(
        senders, receivers, cursor, edge_order, ssort);

    if (use_xb) {
        gather_kernel<true><<<N_REC / 4, 256, 0, stream>>>(
            x, xb, efs, row_ptr, edge_order, ssort, vmb);
    } else {
        gather_kernel<false><<<N_REC / 4, 256, 0, stream>>>(
            x, xb, efs, row_ptr, edge_order, ssort, vmb);
    }

    node_mlp_fused<<<(BATCH * N_REC) / GBM, 512, 0, stream>>>(
        vmb, w1t, ff_b1, w2t, ff_b2, out);
}

// Round 9
// 240.917 us; speedup vs baseline: 1.3486x; 1.0459x over previous
//
#include <hip/hip_runtime.h>
#include <hip/hip_bf16.h>

#define N_SEND 49152
#define N_REC  65536
#define N_EDGES 262144
#define D_MODEL 256
#define EDGE_IN 4
#define EDGE_OUT 64
#define LIN_IN 320
#define LIN_OUT 256
#define BATCH 2

#define GBM 128  // rows per block in fused node GEMM

typedef __attribute__((ext_vector_type(4))) float f32x4;
typedef __attribute__((ext_vector_type(8))) short bf16x8;

static __device__ __forceinline__ unsigned short f2bf(float f) {
    union { float f; unsigned u; } v; v.f = f;
    unsigned r = v.u + 0x7FFF + ((v.u >> 16) & 1);   // round-to-nearest-even
    return (unsigned short)(r >> 16);
}
static __device__ __forceinline__ float bf2f(unsigned short h) {
    union { unsigned u; float f; } v; v.u = ((unsigned)h) << 16; return v.f;
}

// async global->LDS, 16B per lane; LDS dest = wave-uniform base + lane*16
static __device__ __forceinline__ void async_copy16(void* lds_ptr, const void* g_ptr) {
    __builtin_amdgcn_global_load_lds(
        (const __attribute__((address_space(1))) void*)g_ptr,
        (__attribute__((address_space(3))) void*)lds_ptr, 16, 0, 0);
}

// ---------------------------------------------------------------------------
// Fused prep: blockIdx ranges do [conv_x | edge MLP (MFMA) + histogram |
// weight prep]. Unchanged from round 8 (minus one dead LDS store).
__global__ __launch_bounds__(256) void prep_fused(
    const float* __restrict__ x, unsigned short* __restrict__ xb, int nconv,
    const int* __restrict__ receivers, const float* __restrict__ edge_attr,
    const float* __restrict__ ee_w1, const float* __restrict__ ee_b1,
    const float* __restrict__ ee_w2, const float* __restrict__ ee_b2,
    unsigned short* __restrict__ efs, int* __restrict__ counts,
    const float* __restrict__ w1, const float* __restrict__ w2,
    unsigned short* __restrict__ w1t, unsigned short* __restrict__ w2t)
{
    __shared__ __align__(16) unsigned short h_lds[256 * EDGE_OUT];   // 32 KB

    const int bid = blockIdx.x;
    const int tid = threadIdx.x;

    // ---- section 1: x f32 -> xb bf16, 8 elems/thread ----
    if (bid < nconv) {
        const size_t i = ((size_t)bid * 256 + tid) * 8;
        const float4 v0 = *(const float4*)&x[i];
        const float4 v1 = *(const float4*)&x[i + 4];
        bf16x8 o;
        o[0] = (short)f2bf(v0.x); o[1] = (short)f2bf(v0.y);
        o[2] = (short)f2bf(v0.z); o[3] = (short)f2bf(v0.w);
        o[4] = (short)f2bf(v1.x); o[5] = (short)f2bf(v1.y);
        o[6] = (short)f2bf(v1.z); o[7] = (short)f2bf(v1.w);
        *(bf16x8*)&xb[i] = o;
        return;
    }
    const int b2 = bid - nconv;

    // ---- section 2: edge MLP (4->64 relu ->64) on MFMA + histogram ----
    if (b2 < N_EDGES / 256) {
        const int e0 = b2 * 256;
        atomicAdd(&counts[receivers[e0 + tid]], 1);

        // Phase A: thread owns edge e0+tid; 64 outputs, packed bf16x8 writes.
        {
            const float4 ea = *(const float4*)&edge_attr[(size_t)(e0 + tid) * EDGE_IN];
#pragma unroll
            for (int kb = 0; kb < 8; ++kb) {
                bf16x8 hv;
#pragma unroll
                for (int j = 0; j < 8; ++j) {
                    const int k = kb * 8 + j;
                    float a = ee_b1[k];
                    a += ea.x * ee_w1[0 * EDGE_OUT + k];
                    a += ea.y * ee_w1[1 * EDGE_OUT + k];
                    a += ea.z * ee_w1[2 * EDGE_OUT + k];
                    a += ea.w * ee_w1[3 * EDGE_OUT + k];
                    hv[j] = (short)f2bf(fmaxf(a, 0.0f));
                }
                *(bf16x8*)&h_lds[tid * EDGE_OUT + ((kb ^ (tid & 7)) * 8)] = hv;
            }
        }

        // Phase B: ef = h @ W2 + b2 via mfma_16x16x32. Wave w: edges
        // [64w,64w+64). A-frag: lane(m=16t+n16) k=32ch+8hi+j (own-wave rows).
        const int lane = tid & 63, wave = tid >> 6;
        const int n16 = lane & 15, hi = lane >> 4;

        bf16x8 bfr[2][4];
#pragma unroll
        for (int ch = 0; ch < 2; ++ch)
#pragma unroll
            for (int c = 0; c < 4; ++c) {
                bf16x8 b;
#pragma unroll
                for (int j = 0; j < 8; ++j) {
                    const int k = ch * 32 + hi * 8 + j;
                    b[j] = (short)f2bf(ee_w2[k * EDGE_OUT + 16 * c + n16]);
                }
                bfr[ch][c] = b;
            }

        f32x4 acc[4][4];
#pragma unroll
        for (int c = 0; c < 4; ++c) {
            const float bv = ee_b2[16 * c + n16];
#pragma unroll
            for (int t = 0; t < 4; ++t) {
                acc[t][c][0] = bv; acc[t][c][1] = bv; acc[t][c][2] = bv; acc[t][c][3] = bv;
            }
        }

#pragma unroll
        for (int ch = 0; ch < 2; ++ch) {
            bf16x8 af[4];
#pragma unroll
            for (int t = 0; t < 4; ++t) {
                const int row = 64 * wave + 16 * t + n16;
                const int slot = (4 * ch + hi) ^ (row & 7);
                af[t] = *(const bf16x8*)&h_lds[row * EDGE_OUT + slot * 8];
            }
#pragma unroll
            for (int c = 0; c < 4; ++c)
#pragma unroll
                for (int t = 0; t < 4; ++t)
                    acc[t][c] = __builtin_amdgcn_mfma_f32_16x16x32_bf16(af[t], bfr[ch][c], acc[t][c], 0, 0, 0);
        }

        // C/D: edge = e0 + 64w + 16t + 4hi + r, col = 16c + n16.
#pragma unroll
        for (int t = 0; t < 4; ++t)
#pragma unroll
            for (int c = 0; c < 4; ++c)
#pragma unroll
                for (int r = 0; r < 4; ++r)
                    efs[(size_t)(e0 + 64 * wave + 16 * t + 4 * hi + r) * EDGE_OUT + 16 * c + n16] =
                        f2bf(acc[t][c][r]);
        return;
    }

    // ---- section 3: weight transpose+convert ----
    {
        const int t3 = (b2 - N_EDGES / 256) * 256 + tid;
        if (t3 < 256 * LIN_IN) {
            const int n = t3 / LIN_IN, k = t3 - n * LIN_IN;
            w1t[t3] = f2bf(w1[k * LIN_OUT + n]);
        } else {
            const int t2 = t3 - 256 * LIN_IN;
            if (t2 < 256 * 256) {
                const int n = t2 >> 8, k = t2 & 255;
                w2t[t2] = f2bf(w2[k * LIN_OUT + n]);
            }
        }
    }
}

// ---------------------------------------------------------------------------
// Exclusive scan of counts[65536] -> row_ptr[65537], copy to cursor.
__global__ __launch_bounds__(1024) void scan_kernel(
    const int* __restrict__ counts, int* __restrict__ row_ptr,
    int* __restrict__ cursor)
{
    __shared__ int sums[1024];
    const int t = threadIdx.x;
    const int4* c4 = (const int4*)(counts + t * 64);

    int s = 0;
#pragma unroll
    for (int i = 0; i < 16; ++i) { const int4 c = c4[i]; s += c.x + c.y + c.z + c.w; }
    sums[t] = s;
    __syncthreads();

    for (int off = 1; off < 1024; off <<= 1) {
        const int v = (t >= off) ? sums[t - off] : 0;
        __syncthreads();
        sums[t] += v;
        __syncthreads();
    }

    int run = sums[t] - s;
#pragma unroll
    for (int i = 0; i < 16; ++i) {
        const int4 c = c4[i];
        int4 w;
        w.x = run; w.y = run + c.x; w.z = w.y + c.y; w.w = w.z + c.z;
        run = w.w + c.w;
        ((int4*)(row_ptr + t * 64))[i] = w;
        ((int4*)(cursor + t * 64))[i] = w;
    }
    if (t == 1023) row_ptr[N_REC] = run;
}

// ---------------------------------------------------------------------------
// Bucket edges by receiver: edge_order[pos]=e, ssort[pos]=senders[e].
__global__ __launch_bounds__(256) void fill_kernel(
    const int* __restrict__ senders, const int* __restrict__ receivers,
    int* __restrict__ cursor, int* __restrict__ edge_order,
    int* __restrict__ ssort)
{
    const int e = blockIdx.x * 256 + threadIdx.x;
    const int r = receivers[e];
    const int pos = atomicAdd(&cursor[r], 1);
    edge_order[pos] = e;
    ssort[pos] = senders[e];
}

// ---------------------------------------------------------------------------
// Wave-per-receiver gather (unchanged).
template<bool XB>
__global__ __launch_bounds__(256) void gather_kernel(
    const float* __restrict__ x,
    const unsigned short* __restrict__ xb,
    const unsigned short* __restrict__ efs,
    const int* __restrict__ row_ptr,
    const int* __restrict__ edge_order,
    const int* __restrict__ ssort,
    unsigned short* __restrict__ vmb)
{
    const int lane = threadIdx.x & 63;
    const int wave = threadIdx.x >> 6;
    const int r = blockIdx.x * 4 + wave;
    const int beg = row_ptr[r], end = row_ptr[r + 1];
    const int half = lane >> 5, l2 = lane & 31;

    float ax[8] = {0, 0, 0, 0, 0, 0, 0, 0};
    float ae[8] = {0, 0, 0, 0, 0, 0, 0, 0};

    for (int chunk = beg; chunk < end; chunk += 64) {
        const int n = min(64, end - chunk);
        int myidx = 0, myeidx = 0;
        if (chunk + lane < end) {
            myidx = ssort[chunk + lane];
            myeidx = edge_order[chunk + lane];
        }
        for (int i = 0; i < n; ++i) {
            const int s = __shfl(myidx, i);
            const int e = __shfl(myeidx, i);
            const size_t rowbase = (size_t)(half ? N_SEND + s : s) * D_MODEL;
            if (XB) {
                const bf16x8 v = *(const bf16x8*)&xb[rowbase + l2 * 8];
#pragma unroll
                for (int j = 0; j < 8; ++j) ax[j] += bf2f((unsigned short)v[j]);
            } else {
                const float4 v0 = *(const float4*)&x[rowbase + l2 * 8];
                const float4 v1 = *(const float4*)&x[rowbase + l2 * 8 + 4];
                ax[0] += v0.x; ax[1] += v0.y; ax[2] += v0.z; ax[3] += v0.w;
                ax[4] += v1.x; ax[5] += v1.y; ax[6] += v1.z; ax[7] += v1.w;
            }
            if (lane < 8) {
                const bf16x8 w = *(const bf16x8*)&efs[(size_t)e * EDGE_OUT + lane * 8];
#pragma unroll
                for (int j = 0; j < 8; ++j) ae[j] += bf2f((unsigned short)w[j]);
            }
        }
    }

    bf16x8 o;
#pragma unroll
    for (int j = 0; j < 8; ++j) o[j] = (short)f2bf(ax[j]);
    *(bf16x8*)&vmb[((size_t)(half * N_REC + r)) * LIN_IN + l2 * 8] = o;
    if (lane < 8) {
        bf16x8 oe;
#pragma unroll
        for (int j = 0; j < 8; ++j) oe[j] = (short)f2bf(ae[j]);
        *(bf16x8*)&vmb[((size_t)r) * LIN_IN + D_MODEL + lane * 8] = oe;
        *(bf16x8*)&vmb[((size_t)(N_REC + r)) * LIN_IN + D_MODEL + lane * 8] = oe;
    }
}

// ---------------------------------------------------------------------------
// Fused node MLP, single-barrier pipelined K-loops (T3-minimal 2-phase):
// per step {barrier -> stage(next, buf^1) -> ds_read(cur)+MFMA}. One barrier
// per K-step (19 total vs 36): staging DMA overlaps the MFMA window, and the
// vmcnt drain at each barrier covers loads issued a full step earlier.
// Layer-2's first B-stage is hoisted to overlap the h->LDS write phase
// (B-buf0's last readers finished before step-9's leading barrier).
__global__ __launch_bounds__(512, 1) void node_mlp_fused(
    const unsigned short* __restrict__ vmb,   // [2*N_REC][320] bf16
    const unsigned short* __restrict__ w1t,   // [256][320] bf16
    const float* __restrict__ b1,
    const unsigned short* __restrict__ w2t,   // [256][256] bf16
    const float* __restrict__ b2,
    float* __restrict__ out)
{
    __shared__ __align__(16) char lds[114688];
    // [0,16384): A dbuf 2x8KB | [16384,49152): B dbuf 2x16KB | [49152,+65536): h

    const int tid  = threadIdx.x;
    const int lane = tid & 63, wave = tid >> 6;
    const int n16  = lane & 15, hi = lane >> 4;
    const int wr   = wave >> 2, wc = wave & 3;
    const size_t row0 = (size_t)blockIdx.x * GBM;
    char* const hbase = lds + 49152;

    const int f_l = (n16 & 3) ^ ((n16 >> 2) & 3);
    const int hsl = (hi ^ f_l) << 4;

    auto stageA = [&](int kk, int buf) {
        const int row = tid >> 2;
        const int sl = (tid & 3) ^ ((row & 3) ^ ((row >> 2) & 3));
        const unsigned short* g = vmb + (row0 + row) * LIN_IN + kk + sl * 8;
        char* l = lds + (buf << 13) + ((tid >> 6) << 10);
        async_copy16(l, g);
    };
    auto stageB = [&](const unsigned short* BT, int ldk, int kk, int buf) {
#pragma unroll
        for (int p = 0; p < 2; ++p) {
            const int i = p * 512 + tid, row = i >> 2;
            const int sl = (i & 3) ^ ((row & 3) ^ ((row >> 2) & 3));
            const unsigned short* g = BT + (size_t)row * ldk + kk + sl * 8;
            char* l = lds + 16384 + (buf << 14) + (p << 13) + ((tid >> 6) << 10);
            async_copy16(l, g);
        }
    };

    // ---- Layer 1: K=320, 10 steps, single barrier per step ----
    stageA(0, 0); stageB(w1t, LIN_IN, 0, 0);

    f32x4 acc[4][4];
#pragma unroll
    for (int c = 0; c < 4; ++c) {
        const float bv = b1[64 * wc + 16 * c + n16];
#pragma unroll
        for (int t = 0; t < 4; ++t) {
            acc[t][c][0] = bv; acc[t][c][1] = bv; acc[t][c][2] = bv; acc[t][c][3] = bv;
        }
    }

    int cur = 0;
    for (int step = 0; step < LIN_IN / 32; ++step) {
        __syncthreads();   // buf `cur` staged (vmcnt drained at barrier entry)
        if (step + 1 < LIN_IN / 32) {
            stageA((step + 1) * 32, cur ^ 1);
            stageB(w1t, LIN_IN, (step + 1) * 32, cur ^ 1);
        }
        bf16x8 af[4], bf[4];
        const char* Ab = lds + (cur << 13);
        const char* Bb = lds + 16384 + (cur << 14);
#pragma unroll
        for (int t = 0; t < 4; ++t)
            af[t] = *(const bf16x8*)(Ab + (64 * wr + 16 * t + n16) * 64 + hsl);
#pragma unroll
        for (int c = 0; c < 4; ++c)
            bf[c] = *(const bf16x8*)(Bb + (64 * wc + 16 * c + n16) * 64 + hsl);
#pragma unroll
        for (int c = 0; c < 4; ++c)
#pragma unroll
            for (int t = 0; t < 4; ++t)
                acc[t][c] = __builtin_amdgcn_mfma_f32_16x16x32_bf16(af[t], bf[c], acc[t][c], 0, 0, 0);
        cur ^= 1;
    }

    // ---- hoisted layer-2 first B-stage: overlaps the h-write phase.
    // Safe: B-buf0's last readers (step 8) finished before step-9's leading
    // barrier, which every wave has passed.
    stageB(w2t, LIN_OUT, 0, 0);

    // ---- h = relu(acc) -> LDS in stage wire-format ----
#pragma unroll
    for (int t = 0; t < 4; ++t)
#pragma unroll
        for (int c = 0; c < 4; ++c) {
            const int col = 64 * wc + 16 * c + n16;
            const int kc = col >> 5;
            const int b  = (col & 31) * 2;      // byte within 64B row segment
            const int gslot = b >> 4;
#pragma unroll
            for (int r = 0; r < 4; ++r) {
                const int lrow = 64 * wr + 16 * t + 4 * hi + r;
                const int f = (lrow & 3) ^ ((lrow >> 2) & 3);
                *(unsigned short*)(hbase + (kc << 13) + lrow * 64 + (((gslot ^ f) << 4) | (b & 15))) =
                    f2bf(fmaxf(acc[t][c][r], 0.0f));
            }
        }
    __syncthreads();   // h visible to all waves; B2(0) staged

    // ---- Layer 2: K=256, 8 steps; A from h_lds, B staged; barrier at end ----
    f32x4 acc2[4][4];
#pragma unroll
    for (int c = 0; c < 4; ++c) {
        const float bv = b2[64 * wc + 16 * c + n16];
#pragma unroll
        for (int t = 0; t < 4; ++t) {
            acc2[t][c][0] = bv; acc2[t][c][1] = bv; acc2[t][c][2] = bv; acc2[t][c][3] = bv;
        }
    }

    cur = 0;
    for (int step = 0; step < LIN_OUT / 32; ++step) {
        if (step + 1 < LIN_OUT / 32) stageB(w2t, LIN_OUT, (step + 1) * 32, cur ^ 1);

        bf16x8 af[4], bf[4];
        const char* Hb = hbase + (step << 13);
        const char* Bb = lds + 16384 + (cur << 14);
#pragma unroll
        for (int t = 0; t < 4; ++t)
            af[t] = *(const bf16x8*)(Hb + (64 * wr + 16 * t + n16) * 64 + hsl);
#pragma unroll
        for (int c = 0; c < 4; ++c)
            bf[c] = *(const bf16x8*)(Bb + (64 * wc + 16 * c + n16) * 64 + hsl);
#pragma unroll
        for (int c = 0; c < 4; ++c)
#pragma unroll
            for (int t = 0; t < 4; ++t)
                acc2[t][c] = __builtin_amdgcn_mfma_f32_16x16x32_bf16(af[t], bf[c], acc2[t][c], 0, 0, 0);

        __syncthreads();   // next B staged + this step's reads done
        cur ^= 1;
    }

#pragma unroll
    for (int t = 0; t < 4; ++t)
#pragma unroll
        for (int c = 0; c < 4; ++c)
#pragma unroll
            for (int r = 0; r < 4; ++r)
                out[(row0 + 64 * wr + 16 * t + 4 * hi + r) * LIN_OUT + 64 * wc + 16 * c + n16] =
                    acc2[t][c][r];
}

// ---------------------------------------------------------------------------
extern "C" void kernel_launch(void* const* d_in, const int* in_sizes, int n_in,
                              void* d_out, int out_size, void* d_ws, size_t ws_size,
                              hipStream_t stream) {
    const float* x         = (const float*)d_in[0];
    const int*   edge_idx  = (const int*)d_in[1];
    const float* edge_attr = (const float*)d_in[2];
    const float* ee_w1     = (const float*)d_in[3];
    const float* ee_b1     = (const float*)d_in[4];
    const float* ee_w2     = (const float*)d_in[5];
    const float* ee_b2     = (const float*)d_in[6];
    const float* ff_w1     = (const float*)d_in[7];
    const float* ff_b1     = (const float*)d_in[8];
    const float* ff_w2     = (const float*)d_in[9];
    const float* ff_b2     = (const float*)d_in[10];
    float* out = (float*)d_out;

    const int* senders   = edge_idx;
    const int* receivers = edge_idx + N_EDGES;

    // Workspace layout (512B-aligned sub-buffers).
    char* ws = (char*)d_ws;
    size_t off = 0;
    auto alloc = [&](size_t bytes) { char* p = ws + off; off += (bytes + 511) & ~511ull; return p; };

    unsigned short* vmb = (unsigned short*)alloc((size_t)BATCH * N_REC * LIN_IN * 2);   // 83.9 MB
    unsigned short* efs = (unsigned short*)alloc((size_t)N_EDGES * EDGE_OUT * 2);       // 33.6 MB
    unsigned short* w1t = (unsigned short*)alloc((size_t)256 * LIN_IN * 2);
    unsigned short* w2t = (unsigned short*)alloc((size_t)256 * LIN_OUT * 2);
    int* row_ptr        = (int*)alloc((size_t)(N_REC + 1) * 4);
    int* counts         = (int*)alloc((size_t)N_REC * 4);
    int* cursor         = (int*)alloc((size_t)N_REC * 4);
    int* edge_order     = (int*)alloc((size_t)N_EDGES * 4);
    int* ssort          = (int*)alloc((size_t)N_EDGES * 4);
    const size_t base_need = off;
    unsigned short* xb  = (unsigned short*)(ws + off);
    const size_t xb_bytes = (size_t)BATCH * N_SEND * D_MODEL * 2;                        // 50.3 MB
    const bool use_xb = (ws_size >= base_need + xb_bytes);

    hipMemsetAsync(counts, 0, (size_t)N_REC * 4, stream);

    const int nconv = use_xb ? (int)((size_t)BATCH * N_SEND * D_MODEL / 8 / 256) : 0;  // 12288
    const int prep_grid = nconv + N_EDGES / 256 + (256 * LIN_IN + 256 * LIN_OUT + 255) / 256;
    prep_fused<<<prep_grid, 256, 0, stream>>>(
        x, xb, nconv, receivers, edge_attr, ee_w1, ee_b1, ee_w2, ee_b2,
        efs, counts, ff_w1, ff_w2, w1t, w2t);

    scan_kernel<<<1, 1024, 0, stream>>>(counts, row_ptr, cursor);

    fill_kernel<<<N_EDGES / 256, 256, 0, stream>>>(
        senders, receivers, cursor, edge_order, ssort);

    if (use_xb) {
        gather_kernel<true><<<N_REC / 4, 256, 0, stream>>>(
            x, xb, efs, row_ptr, edge_order, ssort, vmb);
    } else {
        gather_kernel<false><<<N_REC / 4, 256, 0, stream>>>(
            x, xb, efs, row_ptr, edge_order, ssort, vmb);
    }

    node_mlp_fused<<<(BATCH * N_REC) / GBM, 512, 0, stream>>>(
        vmb, w1t, ff_b1, w2t, ff_b2, out);
}

// Round 10
// 238.524 us; speedup vs baseline: 1.3621x; 1.0100x over previous
//
#include <hip/hip_runtime.h>
#include <hip/hip_bf16.h>

#define N_SEND 49152
#define N_REC  65536
#define N_EDGES 262144
#define D_MODEL 256
#define EDGE_IN 4
#define EDGE_OUT 64
#define LIN_IN 320
#define LIN_OUT 256
#define BATCH 2

#define GBM 64   // rows per block in fused node GEMM (4 waves, 2 blocks/CU)

typedef __attribute__((ext_vector_type(4))) float f32x4;
typedef __attribute__((ext_vector_type(8))) short bf16x8;

static __device__ __forceinline__ unsigned short f2bf(float f) {
    union { float f; unsigned u; } v; v.f = f;
    unsigned r = v.u + 0x7FFF + ((v.u >> 16) & 1);   // round-to-nearest-even
    return (unsigned short)(r >> 16);
}
static __device__ __forceinline__ float bf2f(unsigned short h) {
    union { unsigned u; float f; } v; v.u = ((unsigned)h) << 16; return v.f;
}

// async global->LDS, 16B per lane; LDS dest = wave-uniform base + lane*16
static __device__ __forceinline__ void async_copy16(void* lds_ptr, const void* g_ptr) {
    __builtin_amdgcn_global_load_lds(
        (const __attribute__((address_space(1))) void*)g_ptr,
        (__attribute__((address_space(3))) void*)lds_ptr, 16, 0, 0);
}

// ---------------------------------------------------------------------------
// Fused prep: blockIdx ranges do [conv_x | edge MLP (MFMA) + histogram |
// weight prep]. Unchanged from round 9.
__global__ __launch_bounds__(256) void prep_fused(
    const float* __restrict__ x, unsigned short* __restrict__ xb, int nconv,
    const int* __restrict__ receivers, const float* __restrict__ edge_attr,
    const float* __restrict__ ee_w1, const float* __restrict__ ee_b1,
    const float* __restrict__ ee_w2, const float* __restrict__ ee_b2,
    unsigned short* __restrict__ efs, int* __restrict__ counts,
    const float* __restrict__ w1, const float* __restrict__ w2,
    unsigned short* __restrict__ w1t, unsigned short* __restrict__ w2t)
{
    __shared__ __align__(16) unsigned short h_lds[256 * EDGE_OUT];   // 32 KB

    const int bid = blockIdx.x;
    const int tid = threadIdx.x;

    // ---- section 1: x f32 -> xb bf16, 8 elems/thread ----
    if (bid < nconv) {
        const size_t i = ((size_t)bid * 256 + tid) * 8;
        const float4 v0 = *(const float4*)&x[i];
        const float4 v1 = *(const float4*)&x[i + 4];
        bf16x8 o;
        o[0] = (short)f2bf(v0.x); o[1] = (short)f2bf(v0.y);
        o[2] = (short)f2bf(v0.z); o[3] = (short)f2bf(v0.w);
        o[4] = (short)f2bf(v1.x); o[5] = (short)f2bf(v1.y);
        o[6] = (short)f2bf(v1.z); o[7] = (short)f2bf(v1.w);
        *(bf16x8*)&xb[i] = o;
        return;
    }
    const int b2 = bid - nconv;

    // ---- section 2: edge MLP (4->64 relu ->64) on MFMA + histogram ----
    if (b2 < N_EDGES / 256) {
        const int e0 = b2 * 256;
        atomicAdd(&counts[receivers[e0 + tid]], 1);

        // Phase A: thread owns edge e0+tid; 64 outputs, packed bf16x8 writes.
        {
            const float4 ea = *(const float4*)&edge_attr[(size_t)(e0 + tid) * EDGE_IN];
#pragma unroll
            for (int kb = 0; kb < 8; ++kb) {
                bf16x8 hv;
#pragma unroll
                for (int j = 0; j < 8; ++j) {
                    const int k = kb * 8 + j;
                    float a = ee_b1[k];
                    a += ea.x * ee_w1[0 * EDGE_OUT + k];
                    a += ea.y * ee_w1[1 * EDGE_OUT + k];
                    a += ea.z * ee_w1[2 * EDGE_OUT + k];
                    a += ea.w * ee_w1[3 * EDGE_OUT + k];
                    hv[j] = (short)f2bf(fmaxf(a, 0.0f));
                }
                *(bf16x8*)&h_lds[tid * EDGE_OUT + ((kb ^ (tid & 7)) * 8)] = hv;
            }
        }

        // Phase B: ef = h @ W2 + b2 via mfma_16x16x32.
        const int lane = tid & 63, wave = tid >> 6;
        const int n16 = lane & 15, hi = lane >> 4;

        bf16x8 bfr[2][4];
#pragma unroll
        for (int ch = 0; ch < 2; ++ch)
#pragma unroll
            for (int c = 0; c < 4; ++c) {
                bf16x8 b;
#pragma unroll
                for (int j = 0; j < 8; ++j) {
                    const int k = ch * 32 + hi * 8 + j;
                    b[j] = (short)f2bf(ee_w2[k * EDGE_OUT + 16 * c + n16]);
                }
                bfr[ch][c] = b;
            }

        f32x4 acc[4][4];
#pragma unroll
        for (int c = 0; c < 4; ++c) {
            const float bv = ee_b2[16 * c + n16];
#pragma unroll
            for (int t = 0; t < 4; ++t) {
                acc[t][c][0] = bv; acc[t][c][1] = bv; acc[t][c][2] = bv; acc[t][c][3] = bv;
            }
        }

#pragma unroll
        for (int ch = 0; ch < 2; ++ch) {
            bf16x8 af[4];
#pragma unroll
            for (int t = 0; t < 4; ++t) {
                const int row = 64 * wave + 16 * t + n16;
                const int slot = (4 * ch + hi) ^ (row & 7);
                af[t] = *(const bf16x8*)&h_lds[row * EDGE_OUT + slot * 8];
            }
#pragma unroll
            for (int c = 0; c < 4; ++c)
#pragma unroll
                for (int t = 0; t < 4; ++t)
                    acc[t][c] = __builtin_amdgcn_mfma_f32_16x16x32_bf16(af[t], bfr[ch][c], acc[t][c], 0, 0, 0);
        }

#pragma unroll
        for (int t = 0; t < 4; ++t)
#pragma unroll
            for (int c = 0; c < 4; ++c)
#pragma unroll
                for (int r = 0; r < 4; ++r)
                    efs[(size_t)(e0 + 64 * wave + 16 * t + 4 * hi + r) * EDGE_OUT + 16 * c + n16] =
                        f2bf(acc[t][c][r]);
        return;
    }

    // ---- section 3: weight transpose+convert ----
    {
        const int t3 = (b2 - N_EDGES / 256) * 256 + tid;
        if (t3 < 256 * LIN_IN) {
            const int n = t3 / LIN_IN, k = t3 - n * LIN_IN;
            w1t[t3] = f2bf(w1[k * LIN_OUT + n]);
        } else {
            const int t2 = t3 - 256 * LIN_IN;
            if (t2 < 256 * 256) {
                const int n = t2 >> 8, k = t2 & 255;
                w2t[t2] = f2bf(w2[k * LIN_OUT + n]);
            }
        }
    }
}

// ---------------------------------------------------------------------------
// Exclusive scan of counts[65536] -> row_ptr[65537], copy to cursor.
__global__ __launch_bounds__(1024) void scan_kernel(
    const int* __restrict__ counts, int* __restrict__ row_ptr,
    int* __restrict__ cursor)
{
    __shared__ int sums[1024];
    const int t = threadIdx.x;
    const int4* c4 = (const int4*)(counts + t * 64);

    int s = 0;
#pragma unroll
    for (int i = 0; i < 16; ++i) { const int4 c = c4[i]; s += c.x + c.y + c.z + c.w; }
    sums[t] = s;
    __syncthreads();

    for (int off = 1; off < 1024; off <<= 1) {
        const int v = (t >= off) ? sums[t - off] : 0;
        __syncthreads();
        sums[t] += v;
        __syncthreads();
    }

    int run = sums[t] - s;
#pragma unroll
    for (int i = 0; i < 16; ++i) {
        const int4 c = c4[i];
        int4 w;
        w.x = run; w.y = run + c.x; w.z = w.y + c.y; w.w = w.z + c.z;
        run = w.w + c.w;
        ((int4*)(row_ptr + t * 64))[i] = w;
        ((int4*)(cursor + t * 64))[i] = w;
    }
    if (t == 1023) row_ptr[N_REC] = run;
}

// ---------------------------------------------------------------------------
// Bucket edges by receiver: edge_order[pos]=e, ssort[pos]=senders[e].
__global__ __launch_bounds__(256) void fill_kernel(
    const int* __restrict__ senders, const int* __restrict__ receivers,
    int* __restrict__ cursor, int* __restrict__ edge_order,
    int* __restrict__ ssort)
{
    const int e = blockIdx.x * 256 + threadIdx.x;
    const int r = receivers[e];
    const int pos = atomicAdd(&cursor[r], 1);
    edge_order[pos] = e;
    ssort[pos] = senders[e];
}

// ---------------------------------------------------------------------------
// Wave-per-receiver gather (unchanged).
template<bool XB>
__global__ __launch_bounds__(256) void gather_kernel(
    const float* __restrict__ x,
    const unsigned short* __restrict__ xb,
    const unsigned short* __restrict__ efs,
    const int* __restrict__ row_ptr,
    const int* __restrict__ edge_order,
    const int* __restrict__ ssort,
    unsigned short* __restrict__ vmb)
{
    const int lane = threadIdx.x & 63;
    const int wave = threadIdx.x >> 6;
    const int r = blockIdx.x * 4 + wave;
    const int beg = row_ptr[r], end = row_ptr[r + 1];
    const int half = lane >> 5, l2 = lane & 31;

    float ax[8] = {0, 0, 0, 0, 0, 0, 0, 0};
    float ae[8] = {0, 0, 0, 0, 0, 0, 0, 0};

    for (int chunk = beg; chunk < end; chunk += 64) {
        const int n = min(64, end - chunk);
        int myidx = 0, myeidx = 0;
        if (chunk + lane < end) {
            myidx = ssort[chunk + lane];
            myeidx = edge_order[chunk + lane];
        }
        for (int i = 0; i < n; ++i) {
            const int s = __shfl(myidx, i);
            const int e = __shfl(myeidx, i);
            const size_t rowbase = (size_t)(half ? N_SEND + s : s) * D_MODEL;
            if (XB) {
                const bf16x8 v = *(const bf16x8*)&xb[rowbase + l2 * 8];
#pragma unroll
                for (int j = 0; j < 8; ++j) ax[j] += bf2f((unsigned short)v[j]);
            } else {
                const float4 v0 = *(const float4*)&x[rowbase + l2 * 8];
                const float4 v1 = *(const float4*)&x[rowbase + l2 * 8 + 4];
                ax[0] += v0.x; ax[1] += v0.y; ax[2] += v0.z; ax[3] += v0.w;
                ax[4] += v1.x; ax[5] += v1.y; ax[6] += v1.z; ax[7] += v1.w;
            }
            if (lane < 8) {
                const bf16x8 w = *(const bf16x8*)&efs[(size_t)e * EDGE_OUT + lane * 8];
#pragma unroll
                for (int j = 0; j < 8; ++j) ae[j] += bf2f((unsigned short)w[j]);
            }
        }
    }

    bf16x8 o;
#pragma unroll
    for (int j = 0; j < 8; ++j) o[j] = (short)f2bf(ax[j]);
    *(bf16x8*)&vmb[((size_t)(half * N_REC + r)) * LIN_IN + l2 * 8] = o;
    if (lane < 8) {
        bf16x8 oe;
#pragma unroll
        for (int j = 0; j < 8; ++j) oe[j] = (short)f2bf(ae[j]);
        *(bf16x8*)&vmb[((size_t)r) * LIN_IN + D_MODEL + lane * 8] = oe;
        *(bf16x8*)&vmb[((size_t)(N_REC + r)) * LIN_IN + D_MODEL + lane * 8] = oe;
    }
}

// ---------------------------------------------------------------------------
// Fused node MLP, GBM=64 / 4 waves / 72KB LDS -> 2 blocks/CU.
// Same single-barrier pipelined K-loops and swizzle paths as round 9, tile
// halved so two INDEPENDENT block pipelines share each CU: while one block
// drains vmcnt at its barrier, the other's waves issue MFMAs (m114 overlap).
// Wave w owns all 64 rows x cols [64w,64w+64): 4x4 16x16 tiles, 16 MFMA/step.
// LDS: A dbuf 2x4KB | B dbuf 2x16KB | h 64x256 bf16 32KB (8 kchunks x 4KB).
__global__ __launch_bounds__(256, 2) void node_mlp_fused(
    const unsigned short* __restrict__ vmb,   // [2*N_REC][320] bf16
    const unsigned short* __restrict__ w1t,   // [256][320] bf16
    const float* __restrict__ b1,
    const unsigned short* __restrict__ w2t,   // [256][256] bf16
    const float* __restrict__ b2,
    float* __restrict__ out)
{
    __shared__ __align__(16) char lds[73728];
    // [0,8192): A dbuf 2x4KB | [8192,40960): B dbuf 2x16KB | [40960,73728): h

    const int tid  = threadIdx.x;
    const int lane = tid & 63, wc = tid >> 6;   // wave index = column span
    const int n16  = lane & 15, hi = lane >> 4;
    const size_t row0 = (size_t)blockIdx.x * GBM;
    char* const hbase = lds + 40960;

    const int f_l = (n16 & 3) ^ ((n16 >> 2) & 3);
    const int hsl = (hi ^ f_l) << 4;

    auto stageA = [&](int kk, int buf) {
        const int row = tid >> 2;               // 0..63
        const int sl = (tid & 3) ^ ((row & 3) ^ ((row >> 2) & 3));
        const unsigned short* g = vmb + (row0 + row) * LIN_IN + kk + sl * 8;
        char* l = lds + (buf << 12) + ((tid >> 6) << 10);
        async_copy16(l, g);
    };
    auto stageB = [&](const unsigned short* BT, int ldk, int kk, int buf) {
#pragma unroll
        for (int p = 0; p < 4; ++p) {
            const int i = p * 256 + tid, row = i >> 2;   // 0..255
            const int sl = (i & 3) ^ ((row & 3) ^ ((row >> 2) & 3));
            const unsigned short* g = BT + (size_t)row * ldk + kk + sl * 8;
            char* l = lds + 8192 + (buf << 14) + (p << 12) + ((tid >> 6) << 10);
            async_copy16(l, g);
        }
    };

    // ---- Layer 1: K=320, 10 steps, single barrier per step ----
    stageA(0, 0); stageB(w1t, LIN_IN, 0, 0);

    f32x4 acc[4][4];
#pragma unroll
    for (int c = 0; c < 4; ++c) {
        const float bv = b1[64 * wc + 16 * c + n16];
#pragma unroll
        for (int t = 0; t < 4; ++t) {
            acc[t][c][0] = bv; acc[t][c][1] = bv; acc[t][c][2] = bv; acc[t][c][3] = bv;
        }
    }

    int cur = 0;
    for (int step = 0; step < LIN_IN / 32; ++step) {
        __syncthreads();   // buf `cur` staged (vmcnt drained at barrier entry)
        if (step + 1 < LIN_IN / 32) {
            stageA((step + 1) * 32, cur ^ 1);
            stageB(w1t, LIN_IN, (step + 1) * 32, cur ^ 1);
        }
        bf16x8 af[4], bf[4];
        const char* Ab = lds + (cur << 12);
        const char* Bb = lds + 8192 + (cur << 14);
#pragma unroll
        for (int t = 0; t < 4; ++t)
            af[t] = *(const bf16x8*)(Ab + (16 * t + n16) * 64 + hsl);
#pragma unroll
        for (int c = 0; c < 4; ++c)
            bf[c] = *(const bf16x8*)(Bb + (64 * wc + 16 * c + n16) * 64 + hsl);
#pragma unroll
        for (int c = 0; c < 4; ++c)
#pragma unroll
            for (int t = 0; t < 4; ++t)
                acc[t][c] = __builtin_amdgcn_mfma_f32_16x16x32_bf16(af[t], bf[c], acc[t][c], 0, 0, 0);
        cur ^= 1;
    }

    // ---- hoisted layer-2 first B-stage: overlaps the h-write phase.
    // Safe: B-buf0's last readers (step 8) finished before step-9's leading
    // barrier, which every wave has passed.
    stageB(w2t, LIN_OUT, 0, 0);

    // ---- h = relu(acc) -> LDS in stage wire-format (8 kchunks x 64 x 64B) --
#pragma unroll
    for (int t = 0; t < 4; ++t)
#pragma unroll
        for (int c = 0; c < 4; ++c) {
            const int col = 64 * wc + 16 * c + n16;
            const int kc = col >> 5;
            const int b  = (col & 31) * 2;      // byte within 64B row segment
            const int gslot = b >> 4;
#pragma unroll
            for (int r = 0; r < 4; ++r) {
                const int lrow = 16 * t + 4 * hi + r;
                const int f = (lrow & 3) ^ ((lrow >> 2) & 3);
                *(unsigned short*)(hbase + (kc << 12) + lrow * 64 + (((gslot ^ f) << 4) | (b & 15))) =
                    f2bf(fmaxf(acc[t][c][r], 0.0f));
            }
        }
    __syncthreads();   // h visible to all waves; B2(0) staged

    // ---- Layer 2: K=256, 8 steps; A from h_lds, B staged; barrier at end ----
    f32x4 acc2[4][4];
#pragma unroll
    for (int c = 0; c < 4; ++c) {
        const float bv = b2[64 * wc + 16 * c + n16];
#pragma unroll
        for (int t = 0; t < 4; ++t) {
            acc2[t][c][0] = bv; acc2[t][c][1] = bv; acc2[t][c][2] = bv; acc2[t][c][3] = bv;
        }
    }

    cur = 0;
    for (int step = 0; step < LIN_OUT / 32; ++step) {
        if (step + 1 < LIN_OUT / 32) stageB(w2t, LIN_OUT, (step + 1) * 32, cur ^ 1);

        bf16x8 af[4], bf[4];
        const char* Hb = hbase + (step << 12);
        const char* Bb = lds + 8192 + (cur << 14);
#pragma unroll
        for (int t = 0; t < 4; ++t)
            af[t] = *(const bf16x8*)(Hb + (16 * t + n16) * 64 + hsl);
#pragma unroll
        for (int c = 0; c < 4; ++c)
            bf[c] = *(const bf16x8*)(Bb + (64 * wc + 16 * c + n16) * 64 + hsl);
#pragma unroll
        for (int c = 0; c < 4; ++c)
#pragma unroll
            for (int t = 0; t < 4; ++t)
                acc2[t][c] = __builtin_amdgcn_mfma_f32_16x16x32_bf16(af[t], bf[c], acc2[t][c], 0, 0, 0);

        __syncthreads();   // next B staged + this step's reads done
        cur ^= 1;
    }

#pragma unroll
    for (int t = 0; t < 4; ++t)
#pragma unroll
        for (int c = 0; c < 4; ++c)
#pragma unroll
            for (int r = 0; r < 4; ++r)
                out[(row0 + 16 * t + 4 * hi + r) * LIN_OUT + 64 * wc + 16 * c + n16] =
                    acc2[t][c][r];
}

// ---------------------------------------------------------------------------
extern "C" void kernel_launch(void* const* d_in, const int* in_sizes, int n_in,
                              void* d_out, int out_size, void* d_ws, size_t ws_size,
                              hipStream_t stream) {
    const float* x         = (const float*)d_in[0];
    const int*   edge_idx  = (const int*)d_in[1];
    const float* edge_attr = (const float*)d_in[2];
    const float* ee_w1     = (const float*)d_in[3];
    const float* ee_b1     = (const float*)d_in[4];
    const float* ee_w2     = (const float*)d_in[5];
    const float* ee_b2     = (const float*)d_in[6];
    const float* ff_w1     = (const float*)d_in[7];
    const float* ff_b1     = (const float*)d_in[8];
    const float* ff_w2     = (const float*)d_in[9];
    const float* ff_b2     = (const float*)d_in[10];
    float* out = (float*)d_out;

    const int* senders   = edge_idx;
    const int* receivers = edge_idx + N_EDGES;

    // Workspace layout (512B-aligned sub-buffers).
    char* ws = (char*)d_ws;
    size_t off = 0;
    auto alloc = [&](size_t bytes) { char* p = ws + off; off += (bytes + 511) & ~511ull; return p; };

    unsigned short* vmb = (unsigned short*)alloc((size_t)BATCH * N_REC * LIN_IN * 2);   // 83.9 MB
    unsigned short* efs = (unsigned short*)alloc((size_t)N_EDGES * EDGE_OUT * 2);       // 33.6 MB
    unsigned short* w1t = (unsigned short*)alloc((size_t)256 * LIN_IN * 2);
    unsigned short* w2t = (unsigned short*)alloc((size_t)256 * LIN_OUT * 2);
    int* row_ptr        = (int*)alloc((size_t)(N_REC + 1) * 4);
    int* counts         = (int*)alloc((size_t)N_REC * 4);
    int* cursor         = (int*)alloc((size_t)N_REC * 4);
    int* edge_order     = (int*)alloc((size_t)N_EDGES * 4);
    int* ssort          = (int*)alloc((size_t)N_EDGES * 4);
    const size_t base_need = off;
    unsigned short* xb  = (unsigned short*)(ws + off);
    const size_t xb_bytes = (size_t)BATCH * N_SEND * D_MODEL * 2;                        // 50.3 MB
    const bool use_xb = (ws_size >= base_need + xb_bytes);

    hipMemsetAsync(counts, 0, (size_t)N_REC * 4, stream);

    const int nconv = use_xb ? (int)((size_t)BATCH * N_SEND * D_MODEL / 8 / 256) : 0;  // 12288
    const int prep_grid = nconv + N_EDGES / 256 + (256 * LIN_IN + 256 * LIN_OUT + 255) / 256;
    prep_fused<<<prep_grid, 256, 0, stream>>>(
        x, xb, nconv, receivers, edge_attr, ee_w1, ee_b1, ee_w2, ee_b2,
        efs, counts, ff_w1, ff_w2, w1t, w2t);

    scan_kernel<<<1, 1024, 0, stream>>>(counts, row_ptr, cursor);

    fill_kernel<<<N_EDGES / 256, 256, 0, stream>>>(
        senders, receivers, cursor, edge_order, ssort);

    if (use_xb) {
        gather_kernel<true><<<N_REC / 4, 256, 0, stream>>>(
            x, xb, efs, row_ptr, edge_order, ssort, vmb);
    } else {
        gather_kernel<false><<<N_REC / 4, 256, 0, stream>>>(
            x, xb, efs, row_ptr, edge_order, ssort, vmb);
    }

    node_mlp_fused<<<(BATCH * N_REC) / GBM, 256, 0, stream>>>(
        vmb, w1t, ff_b1, w2t, ff_b2, out);
}